// Round 13
// baseline (688.144 us; speedup 1.0000x reference)
//
#include <hip/hip_runtime.h>
#include <cstdint>
#include <math.h>

#define T_TOKENS 4096
#define SEQ 2048
#define DM 2048
#define NH 16
#define NKV 8
#define HD 128
#define QDIM 2048   // NH*HD
#define KVDIM 1024  // NKV*HD
#define QKVN 4096   // QDIM + 2*KVDIM
#define INTER 8192
#define GUN 16384   // 2*INTER

typedef int v4i __attribute__((ext_vector_type(4)));
typedef float v4f __attribute__((ext_vector_type(4)));
typedef short s8v __attribute__((ext_vector_type(8)));
typedef short s4v __attribute__((ext_vector_type(4)));
typedef short s2v __attribute__((ext_vector_type(2)));

#define GL16(g, l)                                                                       \
  __builtin_amdgcn_global_load_lds((__attribute__((address_space(1))) const void*)(g),   \
                                   (__attribute__((address_space(3))) void*)(l), 16, 0, 0)

__device__ inline float wave_sum(float v) {
#pragma unroll
  for (int off = 32; off > 0; off >>= 1) v += __shfl_down(v, off);
  return v;
}
__device__ inline float wave_max(float v) {
#pragma unroll
  for (int off = 32; off > 0; off >>= 1) v = fmaxf(v, __shfl_down(v, off));
  return v;
}
__device__ inline float dot4(float4 a, float4 b) {
  return a.x * b.x + a.y * b.y + a.z * b.z + a.w * b.w;
}
__device__ inline int8_t quant1(float v, float s) {
  float q = rintf(v / s);
  q = fminf(fmaxf(q, -127.f), 127.f);
  return (int8_t)(int)q;
}
__device__ inline unsigned short f2bf_rne(float x) {
  unsigned u = __float_as_uint(x);
  return (unsigned short)((u + 0x7FFFu + ((u >> 16) & 1u)) >> 16);
}
__device__ inline float bf2f(unsigned short h) { return __uint_as_float(((unsigned)h) << 16); }

// ---------------- RoPE tables ----------------
__global__ void rope_table_kernel(float* __restrict__ cosT, float* __restrict__ sinT) {
  int s = blockIdx.x, d = threadIdx.x;  // 64 threads
  float inv = 1.0f / powf(10000.0f, (float)d * (1.0f / 64.0f));
  float f = (float)s * inv;
  cosT[s * 64 + d] = cosf(f);
  sinT[s * 64 + d] = sinf(f);
}

// ---------------- per-row weight quant (single-read, register cached) ----------------
__global__ __launch_bounds__(256) void quant_w_kernel(const float* __restrict__ w,
                                                      int8_t* __restrict__ qw,
                                                      float* __restrict__ sw, int K) {
  __shared__ float red[4];
  int row = blockIdx.x, tid = threadIdx.x;
  const float* wr = w + (size_t)row * K;
  int nv = K >> 10;
  float4 v[8];
  float mx = 0.f;
#pragma unroll
  for (int i = 0; i < 8; i++) {
    if (i < nv) {
      v[i] = *(const float4*)(wr + (size_t)(tid + i * 256) * 4);
      mx = fmaxf(mx, fmaxf(fmaxf(fabsf(v[i].x), fabsf(v[i].y)),
                           fmaxf(fabsf(v[i].z), fabsf(v[i].w))));
    }
  }
  mx = wave_max(mx);
  if ((tid & 63) == 0) red[tid >> 6] = mx;
  __syncthreads();
  float m = fmaxf(fmaxf(red[0], red[1]), fmaxf(red[2], red[3]));
  float s = m * (1.0f / 127.0f);
  if (tid == 0) sw[row] = s;
  float sd = (s > 0.f) ? s : 1.f;
  int8_t* qr = qw + (size_t)row * K;
#pragma unroll
  for (int i = 0; i < 8; i++) {
    if (i < nv) {
      char4 o;
      o.x = quant1(v[i].x, sd);
      o.y = quant1(v[i].y, sd);
      o.z = quant1(v[i].z, sd);
      o.w = quant1(v[i].w, sd);
      *(char4*)(qr + (size_t)(tid + i * 256) * 4) = o;
    }
  }
}

// ---------------- gate_up weight quant with 16-col interleaved permutation ----------------
__global__ __launch_bounds__(256) void quant_w_gu_kernel(const float* __restrict__ w,
                                                         int8_t* __restrict__ qw,
                                                         float* __restrict__ sw) {
  __shared__ float red[4];
  int row = blockIdx.x, tid = threadIdx.x;
  const int K = DM;
  int j = (row < INTER) ? row : row - INTER;
  int pr = (j >> 6) * 128 + ((j >> 4) & 3) * 32 + ((row < INTER) ? 0 : 16) + (j & 15);
  const float* wr = w + (size_t)row * K;
  float4 v[2];
  float mx = 0.f;
#pragma unroll
  for (int i = 0; i < 2; i++) {
    v[i] = *(const float4*)(wr + (size_t)(tid + i * 256) * 4);
    mx = fmaxf(mx, fmaxf(fmaxf(fabsf(v[i].x), fabsf(v[i].y)),
                         fmaxf(fabsf(v[i].z), fabsf(v[i].w))));
  }
  mx = wave_max(mx);
  if ((tid & 63) == 0) red[tid >> 6] = mx;
  __syncthreads();
  float m = fmaxf(fmaxf(red[0], red[1]), fmaxf(red[2], red[3]));
  float s = m * (1.0f / 127.0f);
  if (tid == 0) sw[pr] = s;
  float sd = (s > 0.f) ? s : 1.f;
  int8_t* qr = qw + (size_t)pr * K;
#pragma unroll
  for (int i = 0; i < 2; i++) {
    char4 o;
    o.x = quant1(v[i].x, sd);
    o.y = quant1(v[i].y, sd);
    o.z = quant1(v[i].z, sd);
    o.w = quant1(v[i].w, sd);
    *(char4*)(qr + (size_t)(tid + i * 256) * 4) = o;
  }
}

// ---------------- RMSNorm + per-token quant ----------------
__global__ __launch_bounds__(256) void rmsnorm_quant_kernel(const float* __restrict__ x,
                                                            const float* __restrict__ w,
                                                            int8_t* __restrict__ q,
                                                            float* __restrict__ s) {
  __shared__ float red[8];
  int t = blockIdx.x, tid = threadIdx.x;
  const float* xr = x + (size_t)t * DM;
  float4 a = *(const float4*)(xr + tid * 8);
  float4 b = *(const float4*)(xr + tid * 8 + 4);
  float ss = dot4(a, a) + dot4(b, b);
  ss = wave_sum(ss);
  if ((tid & 63) == 0) red[tid >> 6] = ss;
  __syncthreads();
  float tot = red[0] + red[1] + red[2] + red[3];
  float rms = rsqrtf(tot * (1.0f / DM) + 1e-6f);
  float4 wa = *(const float4*)(w + tid * 8);
  float4 wb = *(const float4*)(w + tid * 8 + 4);
  float y[8] = {a.x * rms * wa.x, a.y * rms * wa.y, a.z * rms * wa.z, a.w * rms * wa.w,
                b.x * rms * wb.x, b.y * rms * wb.y, b.z * rms * wb.z, b.w * rms * wb.w};
  float mx = 0.f;
#pragma unroll
  for (int i = 0; i < 8; i++) mx = fmaxf(mx, fabsf(y[i]));
  mx = wave_max(mx);
  if ((tid & 63) == 0) red[4 + (tid >> 6)] = mx;
  __syncthreads();
  float m = fmaxf(fmaxf(red[4], red[5]), fmaxf(red[6], red[7]));
  float sc = fmaxf(m * (1.0f / 127.0f), 1e-8f);
  if (tid == 0) s[t] = sc;
  int8_t* qr = q + (size_t)t * DM + tid * 8;
  char4 o0, o1;
  o0.x = quant1(y[0], sc); o0.y = quant1(y[1], sc); o0.z = quant1(y[2], sc); o0.w = quant1(y[3], sc);
  o1.x = quant1(y[4], sc); o1.y = quant1(y[5], sc); o1.z = quant1(y[6], sc); o1.w = quant1(y[7], sc);
  *(char4*)(qr) = o0;
  *(char4*)(qr + 4) = o1;
}

// ---------------- plain per-token quant of a [*,2048] f32 matrix ----------------
__global__ __launch_bounds__(256) void quant_rows_2048_kernel(const float* __restrict__ x,
                                                              int8_t* __restrict__ q,
                                                              float* __restrict__ s) {
  __shared__ float red[4];
  int t = blockIdx.x, tid = threadIdx.x;
  const float* xr = x + (size_t)t * DM;
  float4 a = *(const float4*)(xr + tid * 8);
  float4 b = *(const float4*)(xr + tid * 8 + 4);
  float y[8] = {a.x, a.y, a.z, a.w, b.x, b.y, b.z, b.w};
  float mx = 0.f;
#pragma unroll
  for (int i = 0; i < 8; i++) mx = fmaxf(mx, fabsf(y[i]));
  mx = wave_max(mx);
  if ((tid & 63) == 0) red[tid >> 6] = mx;
  __syncthreads();
  float m = fmaxf(fmaxf(red[0], red[1]), fmaxf(red[2], red[3]));
  float sc = fmaxf(m * (1.0f / 127.0f), 1e-8f);
  if (tid == 0) s[t] = sc;
  int8_t* qr = q + (size_t)t * DM + tid * 8;
  char4 o0, o1;
  o0.x = quant1(y[0], sc); o0.y = quant1(y[1], sc); o0.z = quant1(y[2], sc); o0.w = quant1(y[3], sc);
  o1.x = quant1(y[4], sc); o1.y = quant1(y[5], sc); o1.z = quant1(y[6], sc); o1.w = quant1(y[7], sc);
  *(char4*)(qr) = o0;
  *(char4*)(qr + 4) = o1;
}

// ---------------- per-token quant of a [*,8192] f32 matrix ----------------
__global__ __launch_bounds__(256) void quant_rows_8192_kernel(const float* __restrict__ x,
                                                              int8_t* __restrict__ q,
                                                              float* __restrict__ s) {
  __shared__ float red[4];
  int t = blockIdx.x, tid = threadIdx.x;
  const float* xr = x + (size_t)t * INTER + tid * 32;
  float y[32];
  float mx = 0.f;
#pragma unroll
  for (int i4 = 0; i4 < 32; i4 += 4) {
    float4 v = *(const float4*)(xr + i4);
    y[i4] = v.x; y[i4 + 1] = v.y; y[i4 + 2] = v.z; y[i4 + 3] = v.w;
    mx = fmaxf(mx, fmaxf(fmaxf(fabsf(v.x), fabsf(v.y)), fmaxf(fabsf(v.z), fabsf(v.w))));
  }
  mx = wave_max(mx);
  if ((tid & 63) == 0) red[tid >> 6] = mx;
  __syncthreads();
  float m = fmaxf(fmaxf(red[0], red[1]), fmaxf(red[2], red[3]));
  float sc = fmaxf(m * (1.0f / 127.0f), 1e-8f);
  if (tid == 0) s[t] = sc;
  int8_t* qr = q + (size_t)t * INTER + tid * 32;
#pragma unroll
  for (int i4 = 0; i4 < 32; i4 += 4) {
    char4 o;
    o.x = quant1(y[i4], sc);
    o.y = quant1(y[i4 + 1], sc);
    o.z = quant1(y[i4 + 2], sc);
    o.w = quant1(y[i4 + 3], sc);
    *(char4*)(qr + i4) = o;
  }
}

// ---------------- RoPE + f32->bf16 hi/lo conversion: Q ----------------
__global__ __launch_bounds__(256) void cvt_q_kernel(const float* __restrict__ qf,
                                                    const float* __restrict__ cosT,
                                                    const float* __restrict__ sinT,
                                                    unsigned short* __restrict__ Qhi,
                                                    unsigned short* __restrict__ Qlo) {
  int t = blockIdx.x, tid = threadIdx.x;
  int sp = t & (SEQ - 1);
  int h = tid >> 4, pb = (tid & 15) * 4;
  const float* row = qf + (size_t)t * QDIM + h * HD;
  float4 x0 = *(const float4*)(row + pb);
  float4 x1 = *(const float4*)(row + pb + 64);
  float4 c = *(const float4*)(cosT + sp * 64 + pb);
  float4 s = *(const float4*)(sinT + sp * 64 + pb);
  float y0[4] = {x0.x * c.x - x1.x * s.x, x0.y * c.y - x1.y * s.y, x0.z * c.z - x1.z * s.z,
                 x0.w * c.w - x1.w * s.w};
  float y1[4] = {x1.x * c.x + x0.x * s.x, x1.y * c.y + x0.y * s.y, x1.z * c.z + x0.z * s.z,
                 x1.w * c.w + x0.w * s.w};
  s4v h0, l0, h1, l1;
#pragma unroll
  for (int e = 0; e < 4; e++) {
    unsigned short hb = f2bf_rne(y0[e]);
    h0[e] = (short)hb;
    l0[e] = (short)f2bf_rne(y0[e] - bf2f(hb));
    hb = f2bf_rne(y1[e]);
    h1[e] = (short)hb;
    l1[e] = (short)f2bf_rne(y1[e] - bf2f(hb));
  }
  size_t o = (size_t)t * QDIM + h * HD + pb;
  *(s4v*)&Qhi[o] = h0;
  *(s4v*)&Qlo[o] = l0;
  *(s4v*)&Qhi[o + 64] = h1;
  *(s4v*)&Qlo[o + 64] = l1;
}

// ---------------- RoPE + conversion: K (layout [(b,g)][s][d]) ----------------
__global__ __launch_bounds__(256) void cvt_k_kernel(const float* __restrict__ kvf,
                                                    const float* __restrict__ cosT,
                                                    const float* __restrict__ sinT,
                                                    unsigned short* __restrict__ Khi,
                                                    unsigned short* __restrict__ Klo) {
  int t = blockIdx.x, tid = threadIdx.x;
  int sp = t & (SEQ - 1);
  int b = t >> 11;
  int g = tid >> 5, pb = (tid & 31) * 2;
  const float* row = kvf + (size_t)t * DM + g * HD;
  float2 x0 = *(const float2*)(row + pb);
  float2 x1 = *(const float2*)(row + pb + 64);
  float2 c = *(const float2*)(cosT + sp * 64 + pb);
  float2 s = *(const float2*)(sinT + sp * 64 + pb);
  float y0[2] = {x0.x * c.x - x1.x * s.x, x0.y * c.y - x1.y * s.y};
  float y1[2] = {x1.x * c.x + x0.x * s.x, x1.y * c.y + x0.y * s.y};
  s2v h0, l0, h1, l1;
#pragma unroll
  for (int e = 0; e < 2; e++) {
    unsigned short hb = f2bf_rne(y0[e]);
    h0[e] = (short)hb;
    l0[e] = (short)f2bf_rne(y0[e] - bf2f(hb));
    hb = f2bf_rne(y1[e]);
    h1[e] = (short)hb;
    l1[e] = (short)f2bf_rne(y1[e] - bf2f(hb));
  }
  size_t o = ((size_t)(b * NKV + g) * SEQ + sp) * HD + pb;
  *(s2v*)&Khi[o] = h0;
  *(s2v*)&Klo[o] = l0;
  *(s2v*)&Khi[o + 64] = h1;
  *(s2v*)&Klo[o + 64] = l1;
}

// ---------------- V transpose + conversion ----------------
// Vt layout per bg: per 32-k tile (8192B): [kc 0-3][d 0-127][e 0-7] bf16
__global__ __launch_bounds__(256) void cvt_v_kernel(const float* __restrict__ kvf,
                                                    unsigned short* __restrict__ Vt) {
  __shared__ float vt[32][132];
  int bg = blockIdx.y;
  int b = bg >> 3, g = bg & 7;
  int s0 = blockIdx.x * 32;
  int tid = threadIdx.x;
#pragma unroll
  for (int i = 0; i < 4; i++) {
    int pos = tid + i * 256;
    int r = pos >> 5, d4 = (pos & 31) * 4;
    *(float4*)&vt[r][d4] =
        *(const float4*)(kvf + (size_t)(b * SEQ + s0 + r) * DM + KVDIM + g * HD + d4);
  }
  __syncthreads();
  int d = tid & 127, half = tid >> 7;
  unsigned short u[16];
#pragma unroll
  for (int i = 0; i < 16; i++) u[i] = f2bf_rne(vt[half * 16 + i][d]);
  unsigned short* dst =
      Vt + (size_t)bg * HD * SEQ + (size_t)(s0 >> 5) * 4096 + (half * 2) * 1024 + d * 8;
  *(s8v*)dst = *(s8v*)&u[0];
  *(s8v*)(dst + 1024) = *(s8v*)&u[8];
}

// ------- int8 GEMM: 2-phase double-buffered (STAGE-early, vmcnt(0)-after-compute) ---------
// 128x128 tile, BK=128, LDS 2x(16K+16K)=64KB -> 2 blocks/CU; XOR swizzle both-sides.
__global__ __launch_bounds__(256) void gemm_i8_kernel(const int8_t* __restrict__ A,
                                                      const float* __restrict__ sA,
                                                      const int8_t* __restrict__ B,
                                                      const float* __restrict__ sB,
                                                      const float* __restrict__ res,
                                                      float* __restrict__ C, int N, int K) {
  __shared__ __align__(16) int8_t lA[2][16384];
  __shared__ __align__(16) int8_t lB[2][16384];
  int tid = threadIdx.x;
  unsigned nx = gridDim.x;
  unsigned hw = blockIdx.y * nx + blockIdx.x;
  unsigned nwg = nx * gridDim.y;
  unsigned work = (hw & 7) * (nwg >> 3) + (hw >> 3);
  int row0 = (int)(work / nx) * 128;
  int col0 = (int)(work % nx) * 128;
  int lane = tid & 63, wid = tid >> 6;
  int wm = (wid >> 1) * 64, wn = (wid & 1) * 64;
  int fr = lane & 15, lq = lane >> 4;

  int rT = tid >> 3;
  int colS = ((tid & 7) << 4) ^ ((rT & 7) << 4);
  const int8_t* gA = A + (size_t)(row0 + rT) * K + colS;
  const int8_t* gB = B + (size_t)(col0 + rT) * K + colS;

  int swzk = (fr & 7) << 4;
  int aoff[4], boff[4];
#pragma unroll
  for (int m = 0; m < 4; m++) {
    aoff[m] = (wm + m * 16 + fr) * 128;
    boff[m] = (wn + m * 16 + fr) * 128;
  }

  v4i acc[4][4];
#pragma unroll
  for (int m = 0; m < 4; m++)
#pragma unroll
    for (int n = 0; n < 4; n++) acc[m][n] = (v4i){0, 0, 0, 0};

#define GSTAGE(t, buf)                                                           \
  do {                                                                           \
    int kk0 = (t) * 128;                                                         \
    _Pragma("unroll") for (int i = 0; i < 4; i++) {                              \
      GL16(gA + kk0 + (size_t)(32 * i) * K, &lA[buf][tid * 16 + i * 4096]);      \
      GL16(gB + kk0 + (size_t)(32 * i) * K, &lB[buf][tid * 16 + i * 4096]);      \
    }                                                                            \
  } while (0)

  int nt = K >> 7;
  GSTAGE(0, 0);
  asm volatile("s_waitcnt vmcnt(0)" ::: "memory");
  __builtin_amdgcn_s_barrier();
  __builtin_amdgcn_sched_barrier(0);
  int cur = 0;
  for (int t = 0; t < nt; ++t) {
    if (t + 1 < nt) GSTAGE(t + 1, cur ^ 1);
#pragma unroll
    for (int kk = 0; kk < 2; kk++) {
      int kc = (kk * 64 + lq * 16) ^ swzk;
      v4i a[4], b[4];
#pragma unroll
      for (int m = 0; m < 4; m++) a[m] = *(const v4i*)&lA[cur][aoff[m] + kc];
#pragma unroll
      for (int n = 0; n < 4; n++) b[n] = *(const v4i*)&lB[cur][boff[n] + kc];
#pragma unroll
      for (int m = 0; m < 4; m++)
#pragma unroll
        for (int n = 0; n < 4; n++)
          acc[m][n] = __builtin_amdgcn_mfma_i32_16x16x64_i8(a[m], b[n], acc[m][n], 0, 0, 0);
    }
    if (t + 1 < nt) {
      asm volatile("s_waitcnt vmcnt(0)" ::: "memory");
      __builtin_amdgcn_s_barrier();
      __builtin_amdgcn_sched_barrier(0);
      cur ^= 1;
    }
  }
#undef GSTAGE
  int rj = lq * 4;
  int cn = fr;
#pragma unroll
  for (int m = 0; m < 4; m++) {
#pragma unroll
    for (int j = 0; j < 4; j++) {
      int rl = row0 + wm + m * 16 + rj + j;
      float sa = sA[rl];
      size_t rowoff = (size_t)rl * N;
#pragma unroll
      for (int n = 0; n < 4; n++) {
        int cg = col0 + wn + n * 16 + cn;
        float v = (float)acc[m][n][j] * sa * sB[cg];
        if (res) v += res[rowoff + cg];
        C[rowoff + cg] = v;
      }
    }
  }
}

// ------- int8 GEMM + fused gelu(gate)*up epilogue, 2-phase dbuf, col-clustered XCD --------
__global__ __launch_bounds__(256) void gemm_gu_fused_kernel(const int8_t* __restrict__ A,
                                                            const float* __restrict__ sA,
                                                            const int8_t* __restrict__ B,
                                                            const float* __restrict__ sB,
                                                            float* __restrict__ act) {
  __shared__ __align__(16) int8_t lA[2][16384];
  __shared__ __align__(16) int8_t lB[2][16384];
  const int K = DM;
  int tid = threadIdx.x;
  unsigned nx = gridDim.x;
  unsigned ny = gridDim.y;
  unsigned hw = blockIdx.y * nx + blockIdx.x;
  unsigned nwg = nx * ny;
  unsigned work = (hw & 7) * (nwg >> 3) + (hw >> 3);
  int row0 = (int)(work % ny) * 128;   // col-clustered: consecutive work shares col panel
  int col0 = (int)(work / ny) * 128;
  int lane = tid & 63, wid = tid >> 6;
  int wm = (wid >> 1) * 64, wn = (wid & 1) * 64;
  int fr = lane & 15, lq = lane >> 4;

  int rT = tid >> 3;
  int colS = ((tid & 7) << 4) ^ ((rT & 7) << 4);
  const int8_t* gA = A + (size_t)(row0 + rT) * K + colS;
  const int8_t* gB = B + (size_t)(col0 + rT) * K + colS;

  int swzk = (fr & 7) << 4;
  int aoff[4], boff[4];
#pragma unroll
  for (int m = 0; m < 4; m++) {
    aoff[m] = (wm + m * 16 + fr) * 128;
    boff[m] = (wn + m * 16 + fr) * 128;
  }

  v4i acc[4][4];
#pragma unroll
  for (int m = 0; m < 4; m++)
#pragma unroll
    for (int n = 0; n < 4; n++) acc[m][n] = (v4i){0, 0, 0, 0};

#define GSTAGE(t, buf)                                                           \
  do {                                                                           \
    int kk0 = (t) * 128;                                                         \
    _Pragma("unroll") for (int i = 0; i < 4; i++) {                              \
      GL16(gA + kk0 + (size_t)(32 * i) * K, &lA[buf][tid * 16 + i * 4096]);      \
      GL16(gB + kk0 + (size_t)(32 * i) * K, &lB[buf][tid * 16 + i * 4096]);      \
    }                                                                            \
  } while (0)

  const int nt = K >> 7;
  GSTAGE(0, 0);
  asm volatile("s_waitcnt vmcnt(0)" ::: "memory");
  __builtin_amdgcn_s_barrier();
  __builtin_amdgcn_sched_barrier(0);
  int cur = 0;
  for (int t = 0; t < nt; ++t) {
    if (t + 1 < nt) GSTAGE(t + 1, cur ^ 1);
#pragma unroll
    for (int kk = 0; kk < 2; kk++) {
      int kc = (kk * 64 + lq * 16) ^ swzk;
      v4i a[4], b[4];
#pragma unroll
      for (int m = 0; m < 4; m++) a[m] = *(const v4i*)&lA[cur][aoff[m] + kc];
#pragma unroll
      for (int n = 0; n < 4; n++) b[n] = *(const v4i*)&lB[cur][boff[n] + kc];
#pragma unroll
      for (int m = 0; m < 4; m++)
#pragma unroll
        for (int n = 0; n < 4; n++)
          acc[m][n] = __builtin_amdgcn_mfma_i32_16x16x64_i8(a[m], b[n], acc[m][n], 0, 0, 0);
    }
    if (t + 1 < nt) {
      asm volatile("s_waitcnt vmcnt(0)" ::: "memory");
      __builtin_amdgcn_s_barrier();
      __builtin_amdgcn_sched_barrier(0);
      cur ^= 1;
    }
  }
#undef GSTAGE
  int rj = lq * 4;
  int cn = fr;
#pragma unroll
  for (int m = 0; m < 4; m++) {
#pragma unroll
    for (int j = 0; j < 4; j++) {
      int rl = row0 + wm + m * 16 + rj + j;
      float sa = sA[rl];
      size_t rowoff = (size_t)rl * INTER;
#pragma unroll
      for (int np = 0; np < 2; np++) {
        float gv = (float)acc[m][np * 2][j] * sa * sB[col0 + wn + (np * 2) * 16 + cn];
        float uv = (float)acc[m][np * 2 + 1][j] * sa * sB[col0 + wn + (np * 2 + 1) * 16 + cn];
        float inner = 0.7978845608028654f * (gv + 0.044715f * gv * gv * gv);
        float gl = 0.5f * gv * (1.0f + tanhf(inner));
        int jg = (col0 >> 1) + (wn >> 1) + np * 16 + cn;
        act[rowoff + jg] = gl * uv;
      }
    }
  }
}

// ---------------- flash attention: paired q-tiles, 256 thr (1 head), 512 blocks ----------
// Ring-3 LDS (76KB -> 2 blocks/CU co-resident), one barrier/tile, fixed-shift softmax.
// XCD-clustered: all 32 blocks of one KV group land on one XCD (K/V L2-resident).
__global__ __launch_bounds__(256, 2) void attn_mfma_kernel(
    const unsigned short* __restrict__ Qhi, const unsigned short* __restrict__ Qlo,
    const unsigned short* __restrict__ Khi, const unsigned short* __restrict__ Klo,
    const unsigned short* __restrict__ Vt, float* __restrict__ out) {
  __shared__ __align__(16) int8_t lkh[3][8192], lkl[3][8192], lvt[3][8192];
  __shared__ unsigned short ps[4][16][32];
  int hwid = blockIdx.y * gridDim.x + blockIdx.x;  // grid = (32,16), 512 wgs
  int work = (hwid & 7) * 64 + (hwid >> 3);        // XCD-bijective remap (2 bg per XCD)
  int bg = work >> 5;
  int rest = work & 31;
  int pi = rest >> 1;
  int hh = rest & 1;
  int qtS = pi, qtL = 31 - pi;                     // paired q-tiles: 66 tiles, constant
  int b = bg >> 3, g = bg & 7;
  int tid = threadIdx.x;
  int lane = tid & 63, w = tid >> 6;               // 4 waves
  int lr = lane & 15, lq = lane >> 4;
  int h = g * 2 + hh;
  int qbS = qtS * 64 + w * 16;
  int qbL = qtL * 64 + w * 16;

  const int8_t* kbh = (const int8_t*)(Khi + (size_t)bg * SEQ * HD);
  const int8_t* kbl = (const int8_t*)(Klo + (size_t)bg * SEQ * HD);
  const int8_t* vb = (const int8_t*)(Vt + (size_t)bg * HD * SEQ);

  int x0 = tid * 16, x1 = x0 + 4096;
  int sK0 = x0 ^ (((x0 >> 8) & 7) << 4);
  int sK1 = x1 ^ (((x1 >> 8) & 7) << 4);

  // Q fragments for both tiles (hi/lo) in registers
  s8v qhS[4], qlS[4], qhL[4], qlL[4];
  {
    size_t qoS = (size_t)(b * SEQ + qbS + lr) * QDIM + h * HD + lq * 8;
    size_t qoL = (size_t)(b * SEQ + qbL + lr) * QDIM + h * HD + lq * 8;
#pragma unroll
    for (int c = 0; c < 4; ++c) {
      qhS[c] = *(const s8v*)(Qhi + qoS + c * 32);
      qlS[c] = *(const s8v*)(Qlo + qoS + c * 32);
      qhL[c] = *(const s8v*)(Qhi + qoL + c * 32);
      qlL[c] = *(const s8v*)(Qlo + qoL + c * 32);
    }
  }

  v4f oaccS[8], oaccL[8];
#pragma unroll
  for (int i = 0; i < 8; ++i) {
    oaccS[i] = (v4f){0.f, 0.f, 0.f, 0.f};
    oaccL[i] = (v4f){0.f, 0.f, 0.f, 0.f};
  }
  float lsumS[4] = {0.f, 0.f, 0.f, 0.f};
  float lsumL[4] = {0.f, 0.f, 0.f, 0.f};
  const float kin2 = 0.0035355339059327374f;  // 2/(sqrt(128)*50)

  int kswz = (lr & 7) << 4;
  int kcol = lq * 16;
  int vbase = lq * 2048 + lr * 16;  // + dt*256

  int ktiles = 2 * qtL + 2;

#define STAGE(kt, buf)                                  \
  do {                                                  \
    size_t kb = (size_t)(kt) * 8192;                    \
    GL16(kbh + kb + sK0, &lkh[buf][x0]);                \
    GL16(kbh + kb + sK1, &lkh[buf][x1]);                \
    GL16(kbl + kb + sK0, &lkl[buf][x0]);                \
    GL16(kbl + kb + sK1, &lkl[buf][x1]);                \
    GL16(vb + kb + x0, &lvt[buf][x0]);                  \
    GL16(vb + kb + x1, &lvt[buf][x1]);                  \
  } while (0)

#define TILE_COMPUTE(qb, qh, ql, oacc, lsum)                                           \
  do {                                                                                 \
    v4f sacc[2];                                                                       \
    __builtin_amdgcn_s_setprio(1);                                                     \
    _Pragma("unroll") for (int t2 = 0; t2 < 2; ++t2) {                                 \
      v4f s1 = (v4f){0.f, 0.f, 0.f, 0.f};                                              \
      v4f s2 = (v4f){0.f, 0.f, 0.f, 0.f};                                              \
      v4f s3 = (v4f){0.f, 0.f, 0.f, 0.f};                                              \
      int rowb = (t2 * 16 + lr) * 256;                                                 \
      _Pragma("unroll") for (int c = 0; c < 4; ++c) {                                  \
        int off = rowb + ((c * 64 + kcol) ^ kswz);                                     \
        s8v kh = *(const s8v*)&lkh[cur][off];                                          \
        s8v kl = *(const s8v*)&lkl[cur][off];                                          \
        s1 = __builtin_amdgcn_mfma_f32_16x16x32_bf16(qh[c], kh, s1, 0, 0, 0);          \
        s2 = __builtin_amdgcn_mfma_f32_16x16x32_bf16(qh[c], kl, s2, 0, 0, 0);          \
        s3 = __builtin_amdgcn_mfma_f32_16x16x32_bf16(ql[c], kh, s3, 0, 0, 0);          \
      }                                                                                \
      sacc[t2] = (s1 + s2) + s3;                                                       \
    }                                                                                  \
    __builtin_amdgcn_s_setprio(0);                                                     \
    _Pragma("unroll") for (int j = 0; j < 4; ++j) {                                    \
      int qg = (qb) + lq * 4 + j;                                                      \
      int k0g = kbase + lr, k1g = kbase + 16 + lr;                                     \
      float z0 = __expf(sacc[0][j] * kin2);                                            \
      float z1 = __expf(sacc[1][j] * kin2);                                            \
      float e0 = __expf(-100.f * __builtin_amdgcn_rcpf(z0 + 1.f));                     \
      float e1 = __expf(-100.f * __builtin_amdgcn_rcpf(z1 + 1.f));                     \
      e0 = (k0g <= qg) ? e0 : 0.f;                                                     \
      e1 = (k1g <= qg) ? e1 : 0.f;                                                     \
      lsum[j] += e0 + e1;                                                              \
      int q = lq * 4 + j;                                                              \
      ps[w][q][lr] = f2bf_rne(e0);                                                     \
      ps[w][q][16 + lr] = f2bf_rne(e1);                                                \
    }                                                                                  \
    s8v pa = *(const s8v*)&ps[w][lr][lq * 8];                                          \
    __builtin_amdgcn_s_setprio(1);                                                     \
    _Pragma("unroll") for (int dt = 0; dt < 8; ++dt) {                                 \
      s8v vh = *(const s8v*)&lvt[cur][vbase + dt * 256];                               \
      oacc[dt] = __builtin_amdgcn_mfma_f32_16x16x32_bf16(pa, vh, oacc[dt], 0, 0, 0);   \
    }                                                                                  \
    __builtin_amdgcn_s_setprio(0);                                                     \
  } while (0)

  STAGE(0, 0);
  STAGE(1, 1);
  int cur = 0;
  for (int kt = 0; kt < ktiles; ++kt) {
    if (kt + 1 < ktiles) {
      asm volatile("s_waitcnt vmcnt(6)" ::: "memory");
    } else {
      asm volatile("s_waitcnt vmcnt(0)" ::: "memory");
    }
    __builtin_amdgcn_s_barrier();
    __builtin_amdgcn_sched_barrier(0);
    int stg = cur + 2;
    if (stg >= 3) stg -= 3;
    if (kt + 2 < ktiles) STAGE(kt + 2, stg);
    int kbase = kt * 32;
    TILE_COMPUTE(qbL, qhL, qlL, oaccL, lsumL);
    if (kbase <= qbS + 15) TILE_COMPUTE(qbS, qhS, qlS, oaccS, lsumS);
    cur = (cur == 2) ? 0 : cur + 1;
  }
#undef TILE_COMPUTE
#undef STAGE

#pragma unroll
  for (int st = 1; st <= 8; st <<= 1)
#pragma unroll
    for (int j = 0; j < 4; ++j) {
      lsumS[j] += __shfl_xor(lsumS[j], st);
      lsumL[j] += __shfl_xor(lsumL[j], st);
    }

  float invS[4], invL[4];
#pragma unroll
  for (int j = 0; j < 4; ++j) {
    invS[j] = 1.f / lsumS[j];
    invL[j] = 1.f / lsumL[j];
  }
  float* obS = out + (size_t)(b * SEQ + qbS) * QDIM + h * HD;
  float* obL = out + (size_t)(b * SEQ + qbL) * QDIM + h * HD;
#pragma unroll
  for (int dt = 0; dt < 8; ++dt)
#pragma unroll
    for (int j = 0; j < 4; ++j) {
      obS[(size_t)(lq * 4 + j) * QDIM + dt * 16 + lr] = oaccS[dt][j] * invS[j];
      obL[(size_t)(lq * 4 + j) * QDIM + dt * 16 + lr] = oaccL[dt][j] * invL[j];
    }
}

extern "C" void kernel_launch(void* const* d_in, const int* in_sizes, int n_in, void* d_out,
                              int out_size, void* d_ws, size_t ws_size, hipStream_t stream) {
  (void)in_sizes; (void)n_in; (void)out_size; (void)ws_size;
  const float* hidden = (const float*)d_in[0];
  const float* w_in_norm = (const float*)d_in[1];
  const float* w_post_norm = (const float*)d_in[2];
  const float* wqkv = (const float*)d_in[3];
  const float* wo = (const float*)d_in[4];
  const float* w_gate_up = (const float*)d_in[5];
  const float* w_down = (const float*)d_in[6];
  float* out = (float*)d_out;

  char* p = (char*)d_ws;
  size_t off = 0;
  auto take = [&](size_t bytes) -> char* {
    char* r = p + off;
    off += (bytes + 255) & ~(size_t)255;
    return r;
  };
  const size_t MB = 1u << 20;
  int8_t* qx = (int8_t*)take((size_t)T_TOKENS * DM);
  float* sx = (float*)take((size_t)T_TOKENS * 4);
  int8_t* qw_qkv = (int8_t*)take((size_t)QKVN * DM);
  float* sw_qkv = (float*)take((size_t)QKVN * 4);
  int8_t* qw_wo = (int8_t*)take((size_t)DM * QDIM);
  float* sw_wo = (float*)take((size_t)DM * 4);
  int8_t* qw_gu = (int8_t*)take((size_t)GUN * DM);
  float* sw_gu = (float*)take((size_t)GUN * 4);
  int8_t* qw_dn = (int8_t*)take((size_t)DM * INTER);
  float* sw_dn = (float*)take((size_t)DM * 4);
  float* cosT = (float*)take((size_t)SEQ * 64 * 4);
  float* sinT = (float*)take((size_t)SEQ * 64 * 4);
  float* x1 = (float*)take((size_t)T_TOKENS * DM * 4);
  float* s_act = (float*)take((size_t)T_TOKENS * 4);
  char* regB = take(96 * MB);
  float* qf32 = (float*)regB;
  float* kvf32 = (float*)regB;
  float* attn_out = (float*)regB;
  unsigned short* Qhi = (unsigned short*)(regB + 32 * MB);
  unsigned short* Qlo = (unsigned short*)(regB + 48 * MB);
  unsigned short* Khi = (unsigned short*)(regB + 64 * MB);
  unsigned short* Klo = (unsigned short*)(regB + 72 * MB);
  unsigned short* Vt = (unsigned short*)(regB + 80 * MB);
  float* act_f32 = (float*)regB;                       // phase-2: [0,32MB)
  int8_t* act_q8 = (int8_t*)(regB + 64 * MB);          // phase-2: [64,96MB)

  rope_table_kernel<<<SEQ, 64, 0, stream>>>(cosT, sinT);
  quant_w_kernel<<<QKVN, 256, 0, stream>>>(wqkv, qw_qkv, sw_qkv, DM);
  quant_w_kernel<<<DM, 256, 0, stream>>>(wo, qw_wo, sw_wo, QDIM);
  quant_w_gu_kernel<<<GUN, 256, 0, stream>>>(w_gate_up, qw_gu, sw_gu);
  quant_w_kernel<<<DM, 256, 0, stream>>>(w_down, qw_dn, sw_dn, INTER);

  // attention block
  rmsnorm_quant_kernel<<<T_TOKENS, 256, 0, stream>>>(hidden, w_in_norm, qx, sx);
  gemm_i8_kernel<<<dim3(QDIM / 128, T_TOKENS / 128), 256, 0, stream>>>(
      qx, sx, qw_qkv, sw_qkv, nullptr, qf32, QDIM, DM);
  cvt_q_kernel<<<T_TOKENS, 256, 0, stream>>>(qf32, cosT, sinT, Qhi, Qlo);
  gemm_i8_kernel<<<dim3(DM / 128, T_TOKENS / 128), 256, 0, stream>>>(
      qx, sx, qw_qkv + (size_t)QDIM * DM, sw_qkv + QDIM, nullptr, kvf32, DM, DM);
  cvt_k_kernel<<<T_TOKENS, 256, 0, stream>>>(kvf32, cosT, sinT, Khi, Klo);
  cvt_v_kernel<<<dim3(SEQ / 32, 16), 256, 0, stream>>>(kvf32, Vt);
  attn_mfma_kernel<<<dim3(32, 16), 256, 0, stream>>>(Qhi, Qlo, Khi, Klo, Vt, attn_out);
  quant_rows_2048_kernel<<<T_TOKENS, 256, 0, stream>>>(attn_out, qx, sx);
  gemm_i8_kernel<<<dim3(DM / 128, T_TOKENS / 128), 256, 0, stream>>>(
      qx, sx, qw_wo, sw_wo, hidden, x1, DM, QDIM);

  // MLP block: fused gelu epilogue writes act f32; quant; single down GEMM
  rmsnorm_quant_kernel<<<T_TOKENS, 256, 0, stream>>>(x1, w_post_norm, qx, sx);
  for (int ch = 0; ch < 4; ++ch) {
    const int8_t* qxc = qx + (size_t)ch * 1024 * DM;
    const float* sxc = sx + (size_t)ch * 1024;
    gemm_gu_fused_kernel<<<dim3(GUN / 128, 1024 / 128), 256, 0, stream>>>(qxc, sxc, qw_gu, sw_gu,
                                                                          act_f32);
    quant_rows_8192_kernel<<<1024, 256, 0, stream>>>(act_f32, act_q8 + (size_t)ch * 1024 * INTER,
                                                     s_act + (size_t)ch * 1024);
  }
  gemm_i8_kernel<<<dim3(DM / 128, T_TOKENS / 128), 256, 0, stream>>>(
      act_q8, s_act, qw_dn, sw_dn, x1, out, DM, INTER);
}

// Round 14
// 640.538 us; speedup vs baseline: 1.0743x; 1.0743x over previous
//
#include <hip/hip_runtime.h>
#include <cstdint>
#include <math.h>

#define T_TOKENS 4096
#define SEQ 2048
#define DM 2048
#define NH 16
#define NKV 8
#define HD 128
#define QDIM 2048   // NH*HD
#define KVDIM 1024  // NKV*HD
#define QKVN 4096   // QDIM + 2*KVDIM
#define INTER 8192
#define GUN 16384   // 2*INTER

typedef int v4i __attribute__((ext_vector_type(4)));
typedef float v4f __attribute__((ext_vector_type(4)));
typedef short s8v __attribute__((ext_vector_type(8)));
typedef short s4v __attribute__((ext_vector_type(4)));
typedef short s2v __attribute__((ext_vector_type(2)));

#define GL16(g, l)                                                                       \
  __builtin_amdgcn_global_load_lds((__attribute__((address_space(1))) const void*)(g),   \
                                   (__attribute__((address_space(3))) void*)(l), 16, 0, 0)

__device__ inline float wave_sum(float v) {
#pragma unroll
  for (int off = 32; off > 0; off >>= 1) v += __shfl_down(v, off);
  return v;
}
__device__ inline float wave_max(float v) {
#pragma unroll
  for (int off = 32; off > 0; off >>= 1) v = fmaxf(v, __shfl_down(v, off));
  return v;
}
__device__ inline float dot4(float4 a, float4 b) {
  return a.x * b.x + a.y * b.y + a.z * b.z + a.w * b.w;
}
__device__ inline int8_t quant1(float v, float s) {
  float q = rintf(v / s);
  q = fminf(fmaxf(q, -127.f), 127.f);
  return (int8_t)(int)q;
}
__device__ inline unsigned short f2bf_rne(float x) {
  unsigned u = __float_as_uint(x);
  return (unsigned short)((u + 0x7FFFu + ((u >> 16) & 1u)) >> 16);
}
__device__ inline float bf2f(unsigned short h) { return __uint_as_float(((unsigned)h) << 16); }

// ---------------- RoPE tables ----------------
__global__ void rope_table_kernel(float* __restrict__ cosT, float* __restrict__ sinT) {
  int s = blockIdx.x, d = threadIdx.x;  // 64 threads
  float inv = 1.0f / powf(10000.0f, (float)d * (1.0f / 64.0f));
  float f = (float)s * inv;
  cosT[s * 64 + d] = cosf(f);
  sinT[s * 64 + d] = sinf(f);
}

// ---------------- per-row weight quant (single-read, register cached) ----------------
__global__ __launch_bounds__(256) void quant_w_kernel(const float* __restrict__ w,
                                                      int8_t* __restrict__ qw,
                                                      float* __restrict__ sw, int K) {
  __shared__ float red[4];
  int row = blockIdx.x, tid = threadIdx.x;
  const float* wr = w + (size_t)row * K;
  int nv = K >> 10;
  float4 v[8];
  float mx = 0.f;
#pragma unroll
  for (int i = 0; i < 8; i++) {
    if (i < nv) {
      v[i] = *(const float4*)(wr + (size_t)(tid + i * 256) * 4);
      mx = fmaxf(mx, fmaxf(fmaxf(fabsf(v[i].x), fabsf(v[i].y)),
                           fmaxf(fabsf(v[i].z), fabsf(v[i].w))));
    }
  }
  mx = wave_max(mx);
  if ((tid & 63) == 0) red[tid >> 6] = mx;
  __syncthreads();
  float m = fmaxf(fmaxf(red[0], red[1]), fmaxf(red[2], red[3]));
  float s = m * (1.0f / 127.0f);
  if (tid == 0) sw[row] = s;
  float sd = (s > 0.f) ? s : 1.f;
  int8_t* qr = qw + (size_t)row * K;
#pragma unroll
  for (int i = 0; i < 8; i++) {
    if (i < nv) {
      char4 o;
      o.x = quant1(v[i].x, sd);
      o.y = quant1(v[i].y, sd);
      o.z = quant1(v[i].z, sd);
      o.w = quant1(v[i].w, sd);
      *(char4*)(qr + (size_t)(tid + i * 256) * 4) = o;
    }
  }
}

// ---------------- gate_up weight quant with 16-col interleaved permutation ----------------
__global__ __launch_bounds__(256) void quant_w_gu_kernel(const float* __restrict__ w,
                                                         int8_t* __restrict__ qw,
                                                         float* __restrict__ sw) {
  __shared__ float red[4];
  int row = blockIdx.x, tid = threadIdx.x;
  const int K = DM;
  int j = (row < INTER) ? row : row - INTER;
  int pr = (j >> 6) * 128 + ((j >> 4) & 3) * 32 + ((row < INTER) ? 0 : 16) + (j & 15);
  const float* wr = w + (size_t)row * K;
  float4 v[2];
  float mx = 0.f;
#pragma unroll
  for (int i = 0; i < 2; i++) {
    v[i] = *(const float4*)(wr + (size_t)(tid + i * 256) * 4);
    mx = fmaxf(mx, fmaxf(fmaxf(fabsf(v[i].x), fabsf(v[i].y)),
                         fmaxf(fabsf(v[i].z), fabsf(v[i].w))));
  }
  mx = wave_max(mx);
  if ((tid & 63) == 0) red[tid >> 6] = mx;
  __syncthreads();
  float m = fmaxf(fmaxf(red[0], red[1]), fmaxf(red[2], red[3]));
  float s = m * (1.0f / 127.0f);
  if (tid == 0) sw[pr] = s;
  float sd = (s > 0.f) ? s : 1.f;
  int8_t* qr = qw + (size_t)pr * K;
#pragma unroll
  for (int i = 0; i < 2; i++) {
    char4 o;
    o.x = quant1(v[i].x, sd);
    o.y = quant1(v[i].y, sd);
    o.z = quant1(v[i].z, sd);
    o.w = quant1(v[i].w, sd);
    *(char4*)(qr + (size_t)(tid + i * 256) * 4) = o;
  }
}

// ---------------- RMSNorm + per-token quant ----------------
__global__ __launch_bounds__(256) void rmsnorm_quant_kernel(const float* __restrict__ x,
                                                            const float* __restrict__ w,
                                                            int8_t* __restrict__ q,
                                                            float* __restrict__ s) {
  __shared__ float red[8];
  int t = blockIdx.x, tid = threadIdx.x;
  const float* xr = x + (size_t)t * DM;
  float4 a = *(const float4*)(xr + tid * 8);
  float4 b = *(const float4*)(xr + tid * 8 + 4);
  float ss = dot4(a, a) + dot4(b, b);
  ss = wave_sum(ss);
  if ((tid & 63) == 0) red[tid >> 6] = ss;
  __syncthreads();
  float tot = red[0] + red[1] + red[2] + red[3];
  float rms = rsqrtf(tot * (1.0f / DM) + 1e-6f);
  float4 wa = *(const float4*)(w + tid * 8);
  float4 wb = *(const float4*)(w + tid * 8 + 4);
  float y[8] = {a.x * rms * wa.x, a.y * rms * wa.y, a.z * rms * wa.z, a.w * rms * wa.w,
                b.x * rms * wb.x, b.y * rms * wb.y, b.z * rms * wb.z, b.w * rms * wb.w};
  float mx = 0.f;
#pragma unroll
  for (int i = 0; i < 8; i++) mx = fmaxf(mx, fabsf(y[i]));
  mx = wave_max(mx);
  if ((tid & 63) == 0) red[4 + (tid >> 6)] = mx;
  __syncthreads();
  float m = fmaxf(fmaxf(red[4], red[5]), fmaxf(red[6], red[7]));
  float sc = fmaxf(m * (1.0f / 127.0f), 1e-8f);
  if (tid == 0) s[t] = sc;
  int8_t* qr = q + (size_t)t * DM + tid * 8;
  char4 o0, o1;
  o0.x = quant1(y[0], sc); o0.y = quant1(y[1], sc); o0.z = quant1(y[2], sc); o0.w = quant1(y[3], sc);
  o1.x = quant1(y[4], sc); o1.y = quant1(y[5], sc); o1.z = quant1(y[6], sc); o1.w = quant1(y[7], sc);
  *(char4*)(qr) = o0;
  *(char4*)(qr + 4) = o1;
}

// ---------------- plain per-token quant of a [*,2048] f32 matrix ----------------
__global__ __launch_bounds__(256) void quant_rows_2048_kernel(const float* __restrict__ x,
                                                              int8_t* __restrict__ q,
                                                              float* __restrict__ s) {
  __shared__ float red[4];
  int t = blockIdx.x, tid = threadIdx.x;
  const float* xr = x + (size_t)t * DM;
  float4 a = *(const float4*)(xr + tid * 8);
  float4 b = *(const float4*)(xr + tid * 8 + 4);
  float y[8] = {a.x, a.y, a.z, a.w, b.x, b.y, b.z, b.w};
  float mx = 0.f;
#pragma unroll
  for (int i = 0; i < 8; i++) mx = fmaxf(mx, fabsf(y[i]));
  mx = wave_max(mx);
  if ((tid & 63) == 0) red[tid >> 6] = mx;
  __syncthreads();
  float m = fmaxf(fmaxf(red[0], red[1]), fmaxf(red[2], red[3]));
  float sc = fmaxf(m * (1.0f / 127.0f), 1e-8f);
  if (tid == 0) s[t] = sc;
  int8_t* qr = q + (size_t)t * DM + tid * 8;
  char4 o0, o1;
  o0.x = quant1(y[0], sc); o0.y = quant1(y[1], sc); o0.z = quant1(y[2], sc); o0.w = quant1(y[3], sc);
  o1.x = quant1(y[4], sc); o1.y = quant1(y[5], sc); o1.z = quant1(y[6], sc); o1.w = quant1(y[7], sc);
  *(char4*)(qr) = o0;
  *(char4*)(qr + 4) = o1;
}

// ---------------- per-token quant of a [*,8192] f32 matrix ----------------
__global__ __launch_bounds__(256) void quant_rows_8192_kernel(const float* __restrict__ x,
                                                              int8_t* __restrict__ q,
                                                              float* __restrict__ s) {
  __shared__ float red[4];
  int t = blockIdx.x, tid = threadIdx.x;
  const float* xr = x + (size_t)t * INTER + tid * 32;
  float y[32];
  float mx = 0.f;
#pragma unroll
  for (int i4 = 0; i4 < 32; i4 += 4) {
    float4 v = *(const float4*)(xr + i4);
    y[i4] = v.x; y[i4 + 1] = v.y; y[i4 + 2] = v.z; y[i4 + 3] = v.w;
    mx = fmaxf(mx, fmaxf(fmaxf(fabsf(v.x), fabsf(v.y)), fmaxf(fabsf(v.z), fabsf(v.w))));
  }
  mx = wave_max(mx);
  if ((tid & 63) == 0) red[tid >> 6] = mx;
  __syncthreads();
  float m = fmaxf(fmaxf(red[0], red[1]), fmaxf(red[2], red[3]));
  float sc = fmaxf(m * (1.0f / 127.0f), 1e-8f);
  if (tid == 0) s[t] = sc;
  int8_t* qr = q + (size_t)t * INTER + tid * 32;
#pragma unroll
  for (int i4 = 0; i4 < 32; i4 += 4) {
    char4 o;
    o.x = quant1(y[i4], sc);
    o.y = quant1(y[i4 + 1], sc);
    o.z = quant1(y[i4 + 2], sc);
    o.w = quant1(y[i4 + 3], sc);
    *(char4*)(qr + i4) = o;
  }
}

// ---------------- RoPE + f32->bf16 hi/lo conversion: Q ----------------
__global__ __launch_bounds__(256) void cvt_q_kernel(const float* __restrict__ qf,
                                                    const float* __restrict__ cosT,
                                                    const float* __restrict__ sinT,
                                                    unsigned short* __restrict__ Qhi,
                                                    unsigned short* __restrict__ Qlo) {
  int t = blockIdx.x, tid = threadIdx.x;
  int sp = t & (SEQ - 1);
  int h = tid >> 4, pb = (tid & 15) * 4;
  const float* row = qf + (size_t)t * QDIM + h * HD;
  float4 x0 = *(const float4*)(row + pb);
  float4 x1 = *(const float4*)(row + pb + 64);
  float4 c = *(const float4*)(cosT + sp * 64 + pb);
  float4 s = *(const float4*)(sinT + sp * 64 + pb);
  float y0[4] = {x0.x * c.x - x1.x * s.x, x0.y * c.y - x1.y * s.y, x0.z * c.z - x1.z * s.z,
                 x0.w * c.w - x1.w * s.w};
  float y1[4] = {x1.x * c.x + x0.x * s.x, x1.y * c.y + x0.y * s.y, x1.z * c.z + x0.z * s.z,
                 x1.w * c.w + x0.w * s.w};
  s4v h0, l0, h1, l1;
#pragma unroll
  for (int e = 0; e < 4; e++) {
    unsigned short hb = f2bf_rne(y0[e]);
    h0[e] = (short)hb;
    l0[e] = (short)f2bf_rne(y0[e] - bf2f(hb));
    hb = f2bf_rne(y1[e]);
    h1[e] = (short)hb;
    l1[e] = (short)f2bf_rne(y1[e] - bf2f(hb));
  }
  size_t o = (size_t)t * QDIM + h * HD + pb;
  *(s4v*)&Qhi[o] = h0;
  *(s4v*)&Qlo[o] = l0;
  *(s4v*)&Qhi[o + 64] = h1;
  *(s4v*)&Qlo[o + 64] = l1;
}

// ---------------- RoPE + conversion: K (layout [(b,g)][s][d]) ----------------
__global__ __launch_bounds__(256) void cvt_k_kernel(const float* __restrict__ kvf,
                                                    const float* __restrict__ cosT,
                                                    const float* __restrict__ sinT,
                                                    unsigned short* __restrict__ Khi,
                                                    unsigned short* __restrict__ Klo) {
  int t = blockIdx.x, tid = threadIdx.x;
  int sp = t & (SEQ - 1);
  int b = t >> 11;
  int g = tid >> 5, pb = (tid & 31) * 2;
  const float* row = kvf + (size_t)t * DM + g * HD;
  float2 x0 = *(const float2*)(row + pb);
  float2 x1 = *(const float2*)(row + pb + 64);
  float2 c = *(const float2*)(cosT + sp * 64 + pb);
  float2 s = *(const float2*)(sinT + sp * 64 + pb);
  float y0[2] = {x0.x * c.x - x1.x * s.x, x0.y * c.y - x1.y * s.y};
  float y1[2] = {x1.x * c.x + x0.x * s.x, x1.y * c.y + x0.y * s.y};
  s2v h0, l0, h1, l1;
#pragma unroll
  for (int e = 0; e < 2; e++) {
    unsigned short hb = f2bf_rne(y0[e]);
    h0[e] = (short)hb;
    l0[e] = (short)f2bf_rne(y0[e] - bf2f(hb));
    hb = f2bf_rne(y1[e]);
    h1[e] = (short)hb;
    l1[e] = (short)f2bf_rne(y1[e] - bf2f(hb));
  }
  size_t o = ((size_t)(b * NKV + g) * SEQ + sp) * HD + pb;
  *(s2v*)&Khi[o] = h0;
  *(s2v*)&Klo[o] = l0;
  *(s2v*)&Khi[o + 64] = h1;
  *(s2v*)&Klo[o + 64] = l1;
}

// ---------------- V transpose + conversion ----------------
// Vt layout per bg: per 32-k tile (8192B): [kc 0-3][d 0-127][e 0-7] bf16
__global__ __launch_bounds__(256) void cvt_v_kernel(const float* __restrict__ kvf,
                                                    unsigned short* __restrict__ Vt) {
  __shared__ float vt[32][132];
  int bg = blockIdx.y;
  int b = bg >> 3, g = bg & 7;
  int s0 = blockIdx.x * 32;
  int tid = threadIdx.x;
#pragma unroll
  for (int i = 0; i < 4; i++) {
    int pos = tid + i * 256;
    int r = pos >> 5, d4 = (pos & 31) * 4;
    *(float4*)&vt[r][d4] =
        *(const float4*)(kvf + (size_t)(b * SEQ + s0 + r) * DM + KVDIM + g * HD + d4);
  }
  __syncthreads();
  int d = tid & 127, half = tid >> 7;
  unsigned short u[16];
#pragma unroll
  for (int i = 0; i < 16; i++) u[i] = f2bf_rne(vt[half * 16 + i][d]);
  unsigned short* dst =
      Vt + (size_t)bg * HD * SEQ + (size_t)(s0 >> 5) * 4096 + (half * 2) * 1024 + d * 8;
  *(s8v*)dst = *(s8v*)&u[0];
  *(s8v*)(dst + 1024) = *(s8v*)&u[8];
}

// ---------------- int8 GEMM (global_load_lds + XOR swizzle, 128x128, templated BK) --------
template <int BK>
__global__ __launch_bounds__(256) void gemm_i8_kernel(const int8_t* __restrict__ A,
                                                      const float* __restrict__ sA,
                                                      const int8_t* __restrict__ B,
                                                      const float* __restrict__ sB,
                                                      const float* __restrict__ res,
                                                      float* __restrict__ C, int N, int K) {
  constexpr int NCH = BK / 16;   // 16B chunks per tile row
  constexpr int RS = 4096 / BK;  // rows covered per issue round (256 thr x 16B)
  constexpr int ISS = BK / 32;   // issue rounds per matrix
  __shared__ __align__(16) int8_t lA[128 * BK];
  __shared__ __align__(16) int8_t lB[128 * BK];
  int tid = threadIdx.x;
  unsigned nx = gridDim.x;
  unsigned hw = blockIdx.y * nx + blockIdx.x;
  unsigned nwg = nx * gridDim.y;
  unsigned work = (hw & 7) * (nwg >> 3) + (hw >> 3);
  int row0 = (int)(work / nx) * 128;
  int col0 = (int)(work % nx) * 128;
  int lane = tid & 63, wid = tid >> 6;
  int wm = (wid >> 1) * 64, wn = (wid & 1) * 64;
  int fr = lane & 15, lq = lane >> 4;

  int rT = tid / NCH;
  int cT = tid % NCH;
  int colS = ((cT ^ (rT & (NCH - 1))) << 4);
  const int8_t* gA = A + (size_t)(row0 + rT) * K + colS;
  const int8_t* gB = B + (size_t)(col0 + rT) * K + colS;
  int8_t* lAd = &lA[tid * 16];
  int8_t* lBd = &lB[tid * 16];

  int swzk = (fr & (NCH - 1)) << 4;
  int aoff[4], boff[4];
#pragma unroll
  for (int m = 0; m < 4; m++) {
    aoff[m] = (wm + m * 16 + fr) * BK;
    boff[m] = (wn + m * 16 + fr) * BK;
  }

  v4i acc[4][4];
#pragma unroll
  for (int m = 0; m < 4; m++)
#pragma unroll
    for (int n = 0; n < 4; n++) acc[m][n] = (v4i){0, 0, 0, 0};

  for (int k0 = 0; k0 < K; k0 += BK) {
#pragma unroll
    for (int i = 0; i < ISS; i++) GL16(gA + k0 + (size_t)(RS * i) * K, lAd + i * 4096);
#pragma unroll
    for (int i = 0; i < ISS; i++) GL16(gB + k0 + (size_t)(RS * i) * K, lBd + i * 4096);
    __syncthreads();
#pragma unroll
    for (int kk = 0; kk < BK / 64; kk++) {
      int kc = (kk * 64 + lq * 16) ^ swzk;
      v4i a[4], b[4];
#pragma unroll
      for (int m = 0; m < 4; m++) a[m] = *(const v4i*)&lA[aoff[m] + kc];
#pragma unroll
      for (int n = 0; n < 4; n++) b[n] = *(const v4i*)&lB[boff[n] + kc];
#pragma unroll
      for (int m = 0; m < 4; m++)
#pragma unroll
        for (int n = 0; n < 4; n++)
          acc[m][n] = __builtin_amdgcn_mfma_i32_16x16x64_i8(a[m], b[n], acc[m][n], 0, 0, 0);
    }
    __syncthreads();
  }
  int rj = lq * 4;
  int cn = fr;
#pragma unroll
  for (int m = 0; m < 4; m++) {
#pragma unroll
    for (int j = 0; j < 4; j++) {
      int rl = row0 + wm + m * 16 + rj + j;
      float sa = sA[rl];
      size_t rowoff = (size_t)rl * N;
#pragma unroll
      for (int n = 0; n < 4; n++) {
        int cg = col0 + wn + n * 16 + cn;
        float v = (float)acc[m][n][j] * sa * sB[cg];
        if (res) v += res[rowoff + cg];
        C[rowoff + cg] = v;
      }
    }
  }
}

// ---------------- int8 GEMM + fused gelu(gate)*up epilogue (permuted gu weights) ----------
// COL-CLUSTERED XCD decode: each XCD owns a narrow band of B (weight) panels -> B L2-resident.
__global__ __launch_bounds__(256) void gemm_gu_fused_kernel(const int8_t* __restrict__ A,
                                                            const float* __restrict__ sA,
                                                            const int8_t* __restrict__ B,
                                                            const float* __restrict__ sB,
                                                            float* __restrict__ act) {
  __shared__ __align__(16) int8_t lA[16384];
  __shared__ __align__(16) int8_t lB[16384];
  const int K = DM;
  int tid = threadIdx.x;
  unsigned nx = gridDim.x;
  unsigned ny = gridDim.y;
  unsigned hw = blockIdx.y * nx + blockIdx.x;
  unsigned nwg = nx * ny;
  unsigned work = (hw & 7) * (nwg >> 3) + (hw >> 3);
  int row0 = (int)(work % ny) * 128;   // col-clustered: consecutive work shares col panel
  int col0 = (int)(work / ny) * 128;
  int lane = tid & 63, wid = tid >> 6;
  int wm = (wid >> 1) * 64, wn = (wid & 1) * 64;
  int fr = lane & 15, lq = lane >> 4;

  int rT = tid >> 3;
  int colS = ((tid & 7) << 4) ^ ((rT & 7) << 4);
  const int8_t* gA = A + (size_t)(row0 + rT) * K + colS;
  const int8_t* gB = B + (size_t)(col0 + rT) * K + colS;
  int8_t* lAd = &lA[tid * 16];
  int8_t* lBd = &lB[tid * 16];

  int swzk = (fr & 7) << 4;
  int aoff[4], boff[4];
#pragma unroll
  for (int m = 0; m < 4; m++) {
    aoff[m] = (wm + m * 16 + fr) * 128;
    boff[m] = (wn + m * 16 + fr) * 128;
  }

  v4i acc[4][4];
#pragma unroll
  for (int m = 0; m < 4; m++)
#pragma unroll
    for (int n = 0; n < 4; n++) acc[m][n] = (v4i){0, 0, 0, 0};

  for (int k0 = 0; k0 < K; k0 += 128) {
#pragma unroll
    for (int i = 0; i < 4; i++) GL16(gA + k0 + (size_t)(32 * i) * K, lAd + i * 4096);
#pragma unroll
    for (int i = 0; i < 4; i++) GL16(gB + k0 + (size_t)(32 * i) * K, lBd + i * 4096);
    __syncthreads();
#pragma unroll
    for (int kk = 0; kk < 2; kk++) {
      int kc = (kk * 64 + lq * 16) ^ swzk;
      v4i a[4], b[4];
#pragma unroll
      for (int m = 0; m < 4; m++) a[m] = *(const v4i*)&lA[aoff[m] + kc];
#pragma unroll
      for (int n = 0; n < 4; n++) b[n] = *(const v4i*)&lB[boff[n] + kc];
#pragma unroll
      for (int m = 0; m < 4; m++)
#pragma unroll
        for (int n = 0; n < 4; n++)
          acc[m][n] = __builtin_amdgcn_mfma_i32_16x16x64_i8(a[m], b[n], acc[m][n], 0, 0, 0);
    }
    __syncthreads();
  }
  int rj = lq * 4;
  int cn = fr;
#pragma unroll
  for (int m = 0; m < 4; m++) {
#pragma unroll
    for (int j = 0; j < 4; j++) {
      int rl = row0 + wm + m * 16 + rj + j;
      float sa = sA[rl];
      size_t rowoff = (size_t)rl * INTER;
#pragma unroll
      for (int np = 0; np < 2; np++) {
        float gv = (float)acc[m][np * 2][j] * sa * sB[col0 + wn + (np * 2) * 16 + cn];
        float uv = (float)acc[m][np * 2 + 1][j] * sa * sB[col0 + wn + (np * 2 + 1) * 16 + cn];
        float inner = 0.7978845608028654f * (gv + 0.044715f * gv * gv * gv);
        float gl = 0.5f * gv * (1.0f + tanhf(inner));
        int jg = (col0 >> 1) + (wn >> 1) + np * 16 + cn;
        act[rowoff + jg] = gl * uv;
      }
    }
  }
}

// ---------------- flash attention: paired q-tiles, 256 thr (1 head), 512 blocks ----------
// Ring-3 LDS (76KB -> 2 blocks/CU co-resident), one barrier/tile, fixed-shift softmax.
// XCD-clustered: all 32 blocks of one KV group land on one XCD (K/V L2-resident).
__global__ __launch_bounds__(256, 2) void attn_mfma_kernel(
    const unsigned short* __restrict__ Qhi, const unsigned short* __restrict__ Qlo,
    const unsigned short* __restrict__ Khi, const unsigned short* __restrict__ Klo,
    const unsigned short* __restrict__ Vt, float* __restrict__ out) {
  __shared__ __align__(16) int8_t lkh[3][8192], lkl[3][8192], lvt[3][8192];
  __shared__ unsigned short ps[4][16][32];
  int hwid = blockIdx.y * gridDim.x + blockIdx.x;  // grid = (32,16), 512 wgs
  int work = (hwid & 7) * 64 + (hwid >> 3);        // XCD-bijective remap (2 bg per XCD)
  int bg = work >> 5;
  int rest = work & 31;
  int pi = rest >> 1;
  int hh = rest & 1;
  int qtS = pi, qtL = 31 - pi;                     // paired q-tiles: 66 tiles, constant
  int b = bg >> 3, g = bg & 7;
  int tid = threadIdx.x;
  int lane = tid & 63, w = tid >> 6;               // 4 waves
  int lr = lane & 15, lq = lane >> 4;
  int h = g * 2 + hh;
  int qbS = qtS * 64 + w * 16;
  int qbL = qtL * 64 + w * 16;

  const int8_t* kbh = (const int8_t*)(Khi + (size_t)bg * SEQ * HD);
  const int8_t* kbl = (const int8_t*)(Klo + (size_t)bg * SEQ * HD);
  const int8_t* vb = (const int8_t*)(Vt + (size_t)bg * HD * SEQ);

  int x0 = tid * 16, x1 = x0 + 4096;
  int sK0 = x0 ^ (((x0 >> 8) & 7) << 4);
  int sK1 = x1 ^ (((x1 >> 8) & 7) << 4);

  // Q fragments for both tiles (hi/lo) in registers
  s8v qhS[4], qlS[4], qhL[4], qlL[4];
  {
    size_t qoS = (size_t)(b * SEQ + qbS + lr) * QDIM + h * HD + lq * 8;
    size_t qoL = (size_t)(b * SEQ + qbL + lr) * QDIM + h * HD + lq * 8;
#pragma unroll
    for (int c = 0; c < 4; ++c) {
      qhS[c] = *(const s8v*)(Qhi + qoS + c * 32);
      qlS[c] = *(const s8v*)(Qlo + qoS + c * 32);
      qhL[c] = *(const s8v*)(Qhi + qoL + c * 32);
      qlL[c] = *(const s8v*)(Qlo + qoL + c * 32);
    }
  }

  v4f oaccS[8], oaccL[8];
#pragma unroll
  for (int i = 0; i < 8; ++i) {
    oaccS[i] = (v4f){0.f, 0.f, 0.f, 0.f};
    oaccL[i] = (v4f){0.f, 0.f, 0.f, 0.f};
  }
  float lsumS[4] = {0.f, 0.f, 0.f, 0.f};
  float lsumL[4] = {0.f, 0.f, 0.f, 0.f};
  const float kin2 = 0.0035355339059327374f;  // 2/(sqrt(128)*50)

  int kswz = (lr & 7) << 4;
  int kcol = lq * 16;
  int vbase = lq * 2048 + lr * 16;  // + dt*256

  int ktiles = 2 * qtL + 2;

#define STAGE(kt, buf)                                  \
  do {                                                  \
    size_t kb = (size_t)(kt) * 8192;                    \
    GL16(kbh + kb + sK0, &lkh[buf][x0]);                \
    GL16(kbh + kb + sK1, &lkh[buf][x1]);                \
    GL16(kbl + kb + sK0, &lkl[buf][x0]);                \
    GL16(kbl + kb + sK1, &lkl[buf][x1]);                \
    GL16(vb + kb + x0, &lvt[buf][x0]);                  \
    GL16(vb + kb + x1, &lvt[buf][x1]);                  \
  } while (0)

#define TILE_COMPUTE(qb, qh, ql, oacc, lsum)                                           \
  do {                                                                                 \
    v4f sacc[2];                                                                       \
    __builtin_amdgcn_s_setprio(1);                                                     \
    _Pragma("unroll") for (int t2 = 0; t2 < 2; ++t2) {                                 \
      v4f s1 = (v4f){0.f, 0.f, 0.f, 0.f};                                              \
      v4f s2 = (v4f){0.f, 0.f, 0.f, 0.f};                                              \
      v4f s3 = (v4f){0.f, 0.f, 0.f, 0.f};                                              \
      int rowb = (t2 * 16 + lr) * 256;                                                 \
      _Pragma("unroll") for (int c = 0; c < 4; ++c) {                                  \
        int off = rowb + ((c * 64 + kcol) ^ kswz);                                     \
        s8v kh = *(const s8v*)&lkh[cur][off];                                          \
        s8v kl = *(const s8v*)&lkl[cur][off];                                          \
        s1 = __builtin_amdgcn_mfma_f32_16x16x32_bf16(qh[c], kh, s1, 0, 0, 0);          \
        s2 = __builtin_amdgcn_mfma_f32_16x16x32_bf16(qh[c], kl, s2, 0, 0, 0);          \
        s3 = __builtin_amdgcn_mfma_f32_16x16x32_bf16(ql[c], kh, s3, 0, 0, 0);          \
      }                                                                                \
      sacc[t2] = (s1 + s2) + s3;                                                       \
    }                                                                                  \
    __builtin_amdgcn_s_setprio(0);                                                     \
    _Pragma("unroll") for (int j = 0; j < 4; ++j) {                                    \
      int qg = (qb) + lq * 4 + j;                                                      \
      int k0g = kbase + lr, k1g = kbase + 16 + lr;                                     \
      float z0 = __expf(sacc[0][j] * kin2);                                            \
      float z1 = __expf(sacc[1][j] * kin2);                                            \
      float e0 = __expf(-100.f * __builtin_amdgcn_rcpf(z0 + 1.f));                     \
      float e1 = __expf(-100.f * __builtin_amdgcn_rcpf(z1 + 1.f));                     \
      e0 = (k0g <= qg) ? e0 : 0.f;                                                     \
      e1 = (k1g <= qg) ? e1 : 0.f;                                                     \
      lsum[j] += e0 + e1;                                                              \
      int q = lq * 4 + j;                                                              \
      ps[w][q][lr] = f2bf_rne(e0);                                                     \
      ps[w][q][16 + lr] = f2bf_rne(e1);                                                \
    }                                                                                  \
    s8v pa = *(const s8v*)&ps[w][lr][lq * 8];                                          \
    __builtin_amdgcn_s_setprio(1);                                                     \
    _Pragma("unroll") for (int dt = 0; dt < 8; ++dt) {                                 \
      s8v vh = *(const s8v*)&lvt[cur][vbase + dt * 256];                               \
      oacc[dt] = __builtin_amdgcn_mfma_f32_16x16x32_bf16(pa, vh, oacc[dt], 0, 0, 0);   \
    }                                                                                  \
    __builtin_amdgcn_s_setprio(0);                                                     \
  } while (0)

  STAGE(0, 0);
  STAGE(1, 1);
  int cur = 0;
  for (int kt = 0; kt < ktiles; ++kt) {
    if (kt + 1 < ktiles) {
      asm volatile("s_waitcnt vmcnt(6)" ::: "memory");
    } else {
      asm volatile("s_waitcnt vmcnt(0)" ::: "memory");
    }
    __builtin_amdgcn_s_barrier();
    __builtin_amdgcn_sched_barrier(0);
    int stg = cur + 2;
    if (stg >= 3) stg -= 3;
    if (kt + 2 < ktiles) STAGE(kt + 2, stg);
    int kbase = kt * 32;
    TILE_COMPUTE(qbL, qhL, qlL, oaccL, lsumL);
    if (kbase <= qbS + 15) TILE_COMPUTE(qbS, qhS, qlS, oaccS, lsumS);
    cur = (cur == 2) ? 0 : cur + 1;
  }
#undef TILE_COMPUTE
#undef STAGE

#pragma unroll
  for (int st = 1; st <= 8; st <<= 1)
#pragma unroll
    for (int j = 0; j < 4; ++j) {
      lsumS[j] += __shfl_xor(lsumS[j], st);
      lsumL[j] += __shfl_xor(lsumL[j], st);
    }

  float invS[4], invL[4];
#pragma unroll
  for (int j = 0; j < 4; ++j) {
    invS[j] = 1.f / lsumS[j];
    invL[j] = 1.f / lsumL[j];
  }
  float* obS = out + (size_t)(b * SEQ + qbS) * QDIM + h * HD;
  float* obL = out + (size_t)(b * SEQ + qbL) * QDIM + h * HD;
#pragma unroll
  for (int dt = 0; dt < 8; ++dt)
#pragma unroll
    for (int j = 0; j < 4; ++j) {
      obS[(size_t)(lq * 4 + j) * QDIM + dt * 16 + lr] = oaccS[dt][j] * invS[j];
      obL[(size_t)(lq * 4 + j) * QDIM + dt * 16 + lr] = oaccL[dt][j] * invL[j];
    }
}

extern "C" void kernel_launch(void* const* d_in, const int* in_sizes, int n_in, void* d_out,
                              int out_size, void* d_ws, size_t ws_size, hipStream_t stream) {
  (void)in_sizes; (void)n_in; (void)out_size; (void)ws_size;
  const float* hidden = (const float*)d_in[0];
  const float* w_in_norm = (const float*)d_in[1];
  const float* w_post_norm = (const float*)d_in[2];
  const float* wqkv = (const float*)d_in[3];
  const float* wo = (const float*)d_in[4];
  const float* w_gate_up = (const float*)d_in[5];
  const float* w_down = (const float*)d_in[6];
  float* out = (float*)d_out;

  char* p = (char*)d_ws;
  size_t off = 0;
  auto take = [&](size_t bytes) -> char* {
    char* r = p + off;
    off += (bytes + 255) & ~(size_t)255;
    return r;
  };
  const size_t MB = 1u << 20;
  int8_t* qx = (int8_t*)take((size_t)T_TOKENS * DM);
  float* sx = (float*)take((size_t)T_TOKENS * 4);
  int8_t* qw_qkv = (int8_t*)take((size_t)QKVN * DM);
  float* sw_qkv = (float*)take((size_t)QKVN * 4);
  int8_t* qw_wo = (int8_t*)take((size_t)DM * QDIM);
  float* sw_wo = (float*)take((size_t)DM * 4);
  int8_t* qw_gu = (int8_t*)take((size_t)GUN * DM);
  float* sw_gu = (float*)take((size_t)GUN * 4);
  int8_t* qw_dn = (int8_t*)take((size_t)DM * INTER);
  float* sw_dn = (float*)take((size_t)DM * 4);
  float* cosT = (float*)take((size_t)SEQ * 64 * 4);
  float* sinT = (float*)take((size_t)SEQ * 64 * 4);
  float* x1 = (float*)take((size_t)T_TOKENS * DM * 4);
  float* s_act = (float*)take((size_t)T_TOKENS * 4);
  char* regB = take(96 * MB);
  float* qf32 = (float*)regB;
  float* kvf32 = (float*)regB;
  float* attn_out = (float*)regB;
  unsigned short* Qhi = (unsigned short*)(regB + 32 * MB);
  unsigned short* Qlo = (unsigned short*)(regB + 48 * MB);
  unsigned short* Khi = (unsigned short*)(regB + 64 * MB);
  unsigned short* Klo = (unsigned short*)(regB + 72 * MB);
  unsigned short* Vt = (unsigned short*)(regB + 80 * MB);
  float* act_f32 = (float*)regB;                       // phase-2: [0,64MB) (2048-row chunk)
  int8_t* act_q8 = (int8_t*)(regB + 64 * MB);          // phase-2: [64,96MB)

  rope_table_kernel<<<SEQ, 64, 0, stream>>>(cosT, sinT);
  quant_w_kernel<<<QKVN, 256, 0, stream>>>(wqkv, qw_qkv, sw_qkv, DM);
  quant_w_kernel<<<DM, 256, 0, stream>>>(wo, qw_wo, sw_wo, QDIM);
  quant_w_gu_kernel<<<GUN, 256, 0, stream>>>(w_gate_up, qw_gu, sw_gu);
  quant_w_kernel<<<DM, 256, 0, stream>>>(w_down, qw_dn, sw_dn, INTER);

  // attention block
  rmsnorm_quant_kernel<<<T_TOKENS, 256, 0, stream>>>(hidden, w_in_norm, qx, sx);
  gemm_i8_kernel<256><<<dim3(QDIM / 128, T_TOKENS / 128), 256, 0, stream>>>(
      qx, sx, qw_qkv, sw_qkv, nullptr, qf32, QDIM, DM);
  cvt_q_kernel<<<T_TOKENS, 256, 0, stream>>>(qf32, cosT, sinT, Qhi, Qlo);
  gemm_i8_kernel<256><<<dim3(DM / 128, T_TOKENS / 128), 256, 0, stream>>>(
      qx, sx, qw_qkv + (size_t)QDIM * DM, sw_qkv + QDIM, nullptr, kvf32, DM, DM);
  cvt_k_kernel<<<T_TOKENS, 256, 0, stream>>>(kvf32, cosT, sinT, Khi, Klo);
  cvt_v_kernel<<<dim3(SEQ / 32, 16), 256, 0, stream>>>(kvf32, Vt);
  attn_mfma_kernel<<<dim3(32, 16), 256, 0, stream>>>(Qhi, Qlo, Khi, Klo, Vt, attn_out);
  quant_rows_2048_kernel<<<T_TOKENS, 256, 0, stream>>>(attn_out, qx, sx);
  gemm_i8_kernel<256><<<dim3(DM / 128, T_TOKENS / 128), 256, 0, stream>>>(
      qx, sx, qw_wo, sw_wo, hidden, x1, DM, QDIM);

  // MLP block: 2 chunks of 2048 rows (act_f32 = 64MB fits regB[0,64))
  rmsnorm_quant_kernel<<<T_TOKENS, 256, 0, stream>>>(x1, w_post_norm, qx, sx);
  for (int ch = 0; ch < 2; ++ch) {
    const int8_t* qxc = qx + (size_t)ch * 2048 * DM;
    const float* sxc = sx + (size_t)ch * 2048;
    gemm_gu_fused_kernel<<<dim3(GUN / 128, 2048 / 128), 256, 0, stream>>>(qxc, sxc, qw_gu, sw_gu,
                                                                          act_f32);
    quant_rows_8192_kernel<<<2048, 256, 0, stream>>>(act_f32, act_q8 + (size_t)ch * 2048 * INTER,
                                                     s_act + (size_t)ch * 2048);
  }
  gemm_i8_kernel<256><<<dim3(DM / 128, T_TOKENS / 128), 256, 0, stream>>>(
      act_q8, s_act, qw_dn, sw_dn, x1, out, DM, INTER);
}

// Round 15
// 625.428 us; speedup vs baseline: 1.1003x; 1.0242x over previous
//
#include <hip/hip_runtime.h>
#include <cstdint>
#include <math.h>

#define T_TOKENS 4096
#define SEQ 2048
#define DM 2048
#define NH 16
#define NKV 8
#define HD 128
#define QDIM 2048   // NH*HD
#define KVDIM 1024  // NKV*HD
#define QKVN 4096   // QDIM + 2*KVDIM
#define INTER 8192
#define GUN 16384   // 2*INTER

typedef int v4i __attribute__((ext_vector_type(4)));
typedef float v4f __attribute__((ext_vector_type(4)));
typedef short s8v __attribute__((ext_vector_type(8)));
typedef short s4v __attribute__((ext_vector_type(4)));
typedef short s2v __attribute__((ext_vector_type(2)));

#define GL16(g, l)                                                                       \
  __builtin_amdgcn_global_load_lds((__attribute__((address_space(1))) const void*)(g),   \
                                   (__attribute__((address_space(3))) void*)(l), 16, 0, 0)

__device__ inline float wave_sum(float v) {
#pragma unroll
  for (int off = 32; off > 0; off >>= 1) v += __shfl_down(v, off);
  return v;
}
__device__ inline float wave_max(float v) {
#pragma unroll
  for (int off = 32; off > 0; off >>= 1) v = fmaxf(v, __shfl_down(v, off));
  return v;
}
__device__ inline float dot4(float4 a, float4 b) {
  return a.x * b.x + a.y * b.y + a.z * b.z + a.w * b.w;
}
__device__ inline int8_t quant1(float v, float s) {
  float q = rintf(v / s);
  q = fminf(fmaxf(q, -127.f), 127.f);
  return (int8_t)(int)q;
}
__device__ inline unsigned short f2bf_rne(float x) {
  unsigned u = __float_as_uint(x);
  return (unsigned short)((u + 0x7FFFu + ((u >> 16) & 1u)) >> 16);
}
__device__ inline float bf2f(unsigned short h) { return __uint_as_float(((unsigned)h) << 16); }

// ---------------- RoPE tables ----------------
__global__ void rope_table_kernel(float* __restrict__ cosT, float* __restrict__ sinT) {
  int s = blockIdx.x, d = threadIdx.x;  // 64 threads
  float inv = 1.0f / powf(10000.0f, (float)d * (1.0f / 64.0f));
  float f = (float)s * inv;
  cosT[s * 64 + d] = cosf(f);
  sinT[s * 64 + d] = sinf(f);
}

// ---------------- per-row weight quant (single-read, register cached) ----------------
__global__ __launch_bounds__(256) void quant_w_kernel(const float* __restrict__ w,
                                                      int8_t* __restrict__ qw,
                                                      float* __restrict__ sw, int K) {
  __shared__ float red[4];
  int row = blockIdx.x, tid = threadIdx.x;
  const float* wr = w + (size_t)row * K;
  int nv = K >> 10;
  float4 v[8];
  float mx = 0.f;
#pragma unroll
  for (int i = 0; i < 8; i++) {
    if (i < nv) {
      v[i] = *(const float4*)(wr + (size_t)(tid + i * 256) * 4);
      mx = fmaxf(mx, fmaxf(fmaxf(fabsf(v[i].x), fabsf(v[i].y)),
                           fmaxf(fabsf(v[i].z), fabsf(v[i].w))));
    }
  }
  mx = wave_max(mx);
  if ((tid & 63) == 0) red[tid >> 6] = mx;
  __syncthreads();
  float m = fmaxf(fmaxf(red[0], red[1]), fmaxf(red[2], red[3]));
  float s = m * (1.0f / 127.0f);
  if (tid == 0) sw[row] = s;
  float sd = (s > 0.f) ? s : 1.f;
  int8_t* qr = qw + (size_t)row * K;
#pragma unroll
  for (int i = 0; i < 8; i++) {
    if (i < nv) {
      char4 o;
      o.x = quant1(v[i].x, sd);
      o.y = quant1(v[i].y, sd);
      o.z = quant1(v[i].z, sd);
      o.w = quant1(v[i].w, sd);
      *(char4*)(qr + (size_t)(tid + i * 256) * 4) = o;
    }
  }
}

// ---------------- gate_up weight quant with 16-col interleaved permutation ----------------
__global__ __launch_bounds__(256) void quant_w_gu_kernel(const float* __restrict__ w,
                                                         int8_t* __restrict__ qw,
                                                         float* __restrict__ sw) {
  __shared__ float red[4];
  int row = blockIdx.x, tid = threadIdx.x;
  const int K = DM;
  int j = (row < INTER) ? row : row - INTER;
  int pr = (j >> 6) * 128 + ((j >> 4) & 3) * 32 + ((row < INTER) ? 0 : 16) + (j & 15);
  const float* wr = w + (size_t)row * K;
  float4 v[2];
  float mx = 0.f;
#pragma unroll
  for (int i = 0; i < 2; i++) {
    v[i] = *(const float4*)(wr + (size_t)(tid + i * 256) * 4);
    mx = fmaxf(mx, fmaxf(fmaxf(fabsf(v[i].x), fabsf(v[i].y)),
                         fmaxf(fabsf(v[i].z), fabsf(v[i].w))));
  }
  mx = wave_max(mx);
  if ((tid & 63) == 0) red[tid >> 6] = mx;
  __syncthreads();
  float m = fmaxf(fmaxf(red[0], red[1]), fmaxf(red[2], red[3]));
  float s = m * (1.0f / 127.0f);
  if (tid == 0) sw[pr] = s;
  float sd = (s > 0.f) ? s : 1.f;
  int8_t* qr = qw + (size_t)pr * K;
#pragma unroll
  for (int i = 0; i < 2; i++) {
    char4 o;
    o.x = quant1(v[i].x, sd);
    o.y = quant1(v[i].y, sd);
    o.z = quant1(v[i].z, sd);
    o.w = quant1(v[i].w, sd);
    *(char4*)(qr + (size_t)(tid + i * 256) * 4) = o;
  }
}

// ---------------- RMSNorm + per-token quant ----------------
__global__ __launch_bounds__(256) void rmsnorm_quant_kernel(const float* __restrict__ x,
                                                            const float* __restrict__ w,
                                                            int8_t* __restrict__ q,
                                                            float* __restrict__ s) {
  __shared__ float red[8];
  int t = blockIdx.x, tid = threadIdx.x;
  const float* xr = x + (size_t)t * DM;
  float4 a = *(const float4*)(xr + tid * 8);
  float4 b = *(const float4*)(xr + tid * 8 + 4);
  float ss = dot4(a, a) + dot4(b, b);
  ss = wave_sum(ss);
  if ((tid & 63) == 0) red[tid >> 6] = ss;
  __syncthreads();
  float tot = red[0] + red[1] + red[2] + red[3];
  float rms = rsqrtf(tot * (1.0f / DM) + 1e-6f);
  float4 wa = *(const float4*)(w + tid * 8);
  float4 wb = *(const float4*)(w + tid * 8 + 4);
  float y[8] = {a.x * rms * wa.x, a.y * rms * wa.y, a.z * rms * wa.z, a.w * rms * wa.w,
                b.x * rms * wb.x, b.y * rms * wb.y, b.z * rms * wb.z, b.w * rms * wb.w};
  float mx = 0.f;
#pragma unroll
  for (int i = 0; i < 8; i++) mx = fmaxf(mx, fabsf(y[i]));
  mx = wave_max(mx);
  if ((tid & 63) == 0) red[4 + (tid >> 6)] = mx;
  __syncthreads();
  float m = fmaxf(fmaxf(red[4], red[5]), fmaxf(red[6], red[7]));
  float sc = fmaxf(m * (1.0f / 127.0f), 1e-8f);
  if (tid == 0) s[t] = sc;
  int8_t* qr = q + (size_t)t * DM + tid * 8;
  char4 o0, o1;
  o0.x = quant1(y[0], sc); o0.y = quant1(y[1], sc); o0.z = quant1(y[2], sc); o0.w = quant1(y[3], sc);
  o1.x = quant1(y[4], sc); o1.y = quant1(y[5], sc); o1.z = quant1(y[6], sc); o1.w = quant1(y[7], sc);
  *(char4*)(qr) = o0;
  *(char4*)(qr + 4) = o1;
}

// ---------------- plain per-token quant of a [*,2048] f32 matrix ----------------
__global__ __launch_bounds__(256) void quant_rows_2048_kernel(const float* __restrict__ x,
                                                              int8_t* __restrict__ q,
                                                              float* __restrict__ s) {
  __shared__ float red[4];
  int t = blockIdx.x, tid = threadIdx.x;
  const float* xr = x + (size_t)t * DM;
  float4 a = *(const float4*)(xr + tid * 8);
  float4 b = *(const float4*)(xr + tid * 8 + 4);
  float y[8] = {a.x, a.y, a.z, a.w, b.x, b.y, b.z, b.w};
  float mx = 0.f;
#pragma unroll
  for (int i = 0; i < 8; i++) mx = fmaxf(mx, fabsf(y[i]));
  mx = wave_max(mx);
  if ((tid & 63) == 0) red[tid >> 6] = mx;
  __syncthreads();
  float m = fmaxf(fmaxf(red[0], red[1]), fmaxf(red[2], red[3]));
  float sc = fmaxf(m * (1.0f / 127.0f), 1e-8f);
  if (tid == 0) s[t] = sc;
  int8_t* qr = q + (size_t)t * DM + tid * 8;
  char4 o0, o1;
  o0.x = quant1(y[0], sc); o0.y = quant1(y[1], sc); o0.z = quant1(y[2], sc); o0.w = quant1(y[3], sc);
  o1.x = quant1(y[4], sc); o1.y = quant1(y[5], sc); o1.z = quant1(y[6], sc); o1.w = quant1(y[7], sc);
  *(char4*)(qr) = o0;
  *(char4*)(qr + 4) = o1;
}

// ---------------- per-token quant of a [*,8192] bf16 matrix ----------------
__global__ __launch_bounds__(256) void quant_rows_8192_bf16_kernel(
    const unsigned short* __restrict__ x, int8_t* __restrict__ q, float* __restrict__ s) {
  __shared__ float red[4];
  int t = blockIdx.x, tid = threadIdx.x;
  const unsigned short* xr = x + (size_t)t * INTER + tid * 32;
  float y[32];
  float mx = 0.f;
#pragma unroll
  for (int i8 = 0; i8 < 32; i8 += 8) {
    s8v v = *(const s8v*)(xr + i8);
#pragma unroll
    for (int j = 0; j < 8; j++) {
      float f = bf2f((unsigned short)v[j]);
      y[i8 + j] = f;
      mx = fmaxf(mx, fabsf(f));
    }
  }
  mx = wave_max(mx);
  if ((tid & 63) == 0) red[tid >> 6] = mx;
  __syncthreads();
  float m = fmaxf(fmaxf(red[0], red[1]), fmaxf(red[2], red[3]));
  float sc = fmaxf(m * (1.0f / 127.0f), 1e-8f);
  if (tid == 0) s[t] = sc;
  int8_t* qr = q + (size_t)t * INTER + tid * 32;
#pragma unroll
  for (int i4 = 0; i4 < 32; i4 += 4) {
    char4 o;
    o.x = quant1(y[i4], sc);
    o.y = quant1(y[i4 + 1], sc);
    o.z = quant1(y[i4 + 2], sc);
    o.w = quant1(y[i4 + 3], sc);
    *(char4*)(qr + i4) = o;
  }
}

// ---------------- RoPE + f32->bf16 hi/lo conversion: Q ----------------
__global__ __launch_bounds__(256) void cvt_q_kernel(const float* __restrict__ qf,
                                                    const float* __restrict__ cosT,
                                                    const float* __restrict__ sinT,
                                                    unsigned short* __restrict__ Qhi,
                                                    unsigned short* __restrict__ Qlo) {
  int t = blockIdx.x, tid = threadIdx.x;
  int sp = t & (SEQ - 1);
  int h = tid >> 4, pb = (tid & 15) * 4;
  const float* row = qf + (size_t)t * QDIM + h * HD;
  float4 x0 = *(const float4*)(row + pb);
  float4 x1 = *(const float4*)(row + pb + 64);
  float4 c = *(const float4*)(cosT + sp * 64 + pb);
  float4 s = *(const float4*)(sinT + sp * 64 + pb);
  float y0[4] = {x0.x * c.x - x1.x * s.x, x0.y * c.y - x1.y * s.y, x0.z * c.z - x1.z * s.z,
                 x0.w * c.w - x1.w * s.w};
  float y1[4] = {x1.x * c.x + x0.x * s.x, x1.y * c.y + x0.y * s.y, x1.z * c.z + x0.z * s.z,
                 x1.w * c.w + x0.w * s.w};
  s4v h0, l0, h1, l1;
#pragma unroll
  for (int e = 0; e < 4; e++) {
    unsigned short hb = f2bf_rne(y0[e]);
    h0[e] = (short)hb;
    l0[e] = (short)f2bf_rne(y0[e] - bf2f(hb));
    hb = f2bf_rne(y1[e]);
    h1[e] = (short)hb;
    l1[e] = (short)f2bf_rne(y1[e] - bf2f(hb));
  }
  size_t o = (size_t)t * QDIM + h * HD + pb;
  *(s4v*)&Qhi[o] = h0;
  *(s4v*)&Qlo[o] = l0;
  *(s4v*)&Qhi[o + 64] = h1;
  *(s4v*)&Qlo[o + 64] = l1;
}

// ---------------- RoPE + conversion: K (layout [(b,g)][s][d]) ----------------
__global__ __launch_bounds__(256) void cvt_k_kernel(const float* __restrict__ kvf,
                                                    const float* __restrict__ cosT,
                                                    const float* __restrict__ sinT,
                                                    unsigned short* __restrict__ Khi,
                                                    unsigned short* __restrict__ Klo) {
  int t = blockIdx.x, tid = threadIdx.x;
  int sp = t & (SEQ - 1);
  int b = t >> 11;
  int g = tid >> 5, pb = (tid & 31) * 2;
  const float* row = kvf + (size_t)t * DM + g * HD;
  float2 x0 = *(const float2*)(row + pb);
  float2 x1 = *(const float2*)(row + pb + 64);
  float2 c = *(const float2*)(cosT + sp * 64 + pb);
  float2 s = *(const float2*)(sinT + sp * 64 + pb);
  float y0[2] = {x0.x * c.x - x1.x * s.x, x0.y * c.y - x1.y * s.y};
  float y1[2] = {x1.x * c.x + x0.x * s.x, x1.y * c.y + x0.y * s.y};
  s2v h0, l0, h1, l1;
#pragma unroll
  for (int e = 0; e < 2; e++) {
    unsigned short hb = f2bf_rne(y0[e]);
    h0[e] = (short)hb;
    l0[e] = (short)f2bf_rne(y0[e] - bf2f(hb));
    hb = f2bf_rne(y1[e]);
    h1[e] = (short)hb;
    l1[e] = (short)f2bf_rne(y1[e] - bf2f(hb));
  }
  size_t o = ((size_t)(b * NKV + g) * SEQ + sp) * HD + pb;
  *(s2v*)&Khi[o] = h0;
  *(s2v*)&Klo[o] = l0;
  *(s2v*)&Khi[o + 64] = h1;
  *(s2v*)&Klo[o + 64] = l1;
}

// ---------------- V transpose + conversion ----------------
// Vt layout per bg: per 32-k tile (8192B): [kc 0-3][d 0-127][e 0-7] bf16
__global__ __launch_bounds__(256) void cvt_v_kernel(const float* __restrict__ kvf,
                                                    unsigned short* __restrict__ Vt) {
  __shared__ float vt[32][132];
  int bg = blockIdx.y;
  int b = bg >> 3, g = bg & 7;
  int s0 = blockIdx.x * 32;
  int tid = threadIdx.x;
#pragma unroll
  for (int i = 0; i < 4; i++) {
    int pos = tid + i * 256;
    int r = pos >> 5, d4 = (pos & 31) * 4;
    *(float4*)&vt[r][d4] =
        *(const float4*)(kvf + (size_t)(b * SEQ + s0 + r) * DM + KVDIM + g * HD + d4);
  }
  __syncthreads();
  int d = tid & 127, half = tid >> 7;
  unsigned short u[16];
#pragma unroll
  for (int i = 0; i < 16; i++) u[i] = f2bf_rne(vt[half * 16 + i][d]);
  unsigned short* dst =
      Vt + (size_t)bg * HD * SEQ + (size_t)(s0 >> 5) * 4096 + (half * 2) * 1024 + d * 8;
  *(s8v*)dst = *(s8v*)&u[0];
  *(s8v*)(dst + 1024) = *(s8v*)&u[8];
}

// ---------------- int8 GEMM (global_load_lds + XOR swizzle, 128x128, templated BK) --------
template <int BK>
__global__ __launch_bounds__(256) void gemm_i8_kernel(const int8_t* __restrict__ A,
                                                      const float* __restrict__ sA,
                                                      const int8_t* __restrict__ B,
                                                      const float* __restrict__ sB,
                                                      const float* __restrict__ res,
                                                      float* __restrict__ C, int N, int K) {
  constexpr int NCH = BK / 16;   // 16B chunks per tile row
  constexpr int RS = 4096 / BK;  // rows covered per issue round (256 thr x 16B)
  constexpr int ISS = BK / 32;   // issue rounds per matrix
  __shared__ __align__(16) int8_t lA[128 * BK];
  __shared__ __align__(16) int8_t lB[128 * BK];
  int tid = threadIdx.x;
  unsigned nx = gridDim.x;
  unsigned hw = blockIdx.y * nx + blockIdx.x;
  unsigned nwg = nx * gridDim.y;
  unsigned work = (hw & 7) * (nwg >> 3) + (hw >> 3);
  int row0 = (int)(work / nx) * 128;
  int col0 = (int)(work % nx) * 128;
  int lane = tid & 63, wid = tid >> 6;
  int wm = (wid >> 1) * 64, wn = (wid & 1) * 64;
  int fr = lane & 15, lq = lane >> 4;

  int rT = tid / NCH;
  int cT = tid % NCH;
  int colS = ((cT ^ (rT & (NCH - 1))) << 4);
  const int8_t* gA = A + (size_t)(row0 + rT) * K + colS;
  const int8_t* gB = B + (size_t)(col0 + rT) * K + colS;
  int8_t* lAd = &lA[tid * 16];
  int8_t* lBd = &lB[tid * 16];

  int swzk = (fr & (NCH - 1)) << 4;
  int aoff[4], boff[4];
#pragma unroll
  for (int m = 0; m < 4; m++) {
    aoff[m] = (wm + m * 16 + fr) * BK;
    boff[m] = (wn + m * 16 + fr) * BK;
  }

  v4i acc[4][4];
#pragma unroll
  for (int m = 0; m < 4; m++)
#pragma unroll
    for (int n = 0; n < 4; n++) acc[m][n] = (v4i){0, 0, 0, 0};

  for (int k0 = 0; k0 < K; k0 += BK) {
#pragma unroll
    for (int i = 0; i < ISS; i++) GL16(gA + k0 + (size_t)(RS * i) * K, lAd + i * 4096);
#pragma unroll
    for (int i = 0; i < ISS; i++) GL16(gB + k0 + (size_t)(RS * i) * K, lBd + i * 4096);
    __syncthreads();
#pragma unroll
    for (int kk = 0; kk < BK / 64; kk++) {
      int kc = (kk * 64 + lq * 16) ^ swzk;
      v4i a[4], b[4];
#pragma unroll
      for (int m = 0; m < 4; m++) a[m] = *(const v4i*)&lA[aoff[m] + kc];
#pragma unroll
      for (int n = 0; n < 4; n++) b[n] = *(const v4i*)&lB[boff[n] + kc];
#pragma unroll
      for (int m = 0; m < 4; m++)
#pragma unroll
        for (int n = 0; n < 4; n++)
          acc[m][n] = __builtin_amdgcn_mfma_i32_16x16x64_i8(a[m], b[n], acc[m][n], 0, 0, 0);
    }
    __syncthreads();
  }
  int rj = lq * 4;
  int cn = fr;
#pragma unroll
  for (int m = 0; m < 4; m++) {
#pragma unroll
    for (int j = 0; j < 4; j++) {
      int rl = row0 + wm + m * 16 + rj + j;
      float sa = sA[rl];
      size_t rowoff = (size_t)rl * N;
#pragma unroll
      for (int n = 0; n < 4; n++) {
        int cg = col0 + wn + n * 16 + cn;
        float v = (float)acc[m][n][j] * sa * sB[cg];
        if (res) v += res[rowoff + cg];
        C[rowoff + cg] = v;
      }
    }
  }
}

// ---------------- int8 GEMM + fused gelu(gate)*up epilogue -> bf16 act ----------
// COL-CLUSTERED XCD decode: each XCD owns a narrow band of B (weight) panels -> B L2-resident.
__global__ __launch_bounds__(256) void gemm_gu_fused_kernel(const int8_t* __restrict__ A,
                                                            const float* __restrict__ sA,
                                                            const int8_t* __restrict__ B,
                                                            const float* __restrict__ sB,
                                                            unsigned short* __restrict__ act) {
  __shared__ __align__(16) int8_t lA[16384];
  __shared__ __align__(16) int8_t lB[16384];
  const int K = DM;
  int tid = threadIdx.x;
  unsigned nx = gridDim.x;
  unsigned ny = gridDim.y;
  unsigned hw = blockIdx.y * nx + blockIdx.x;
  unsigned nwg = nx * ny;
  unsigned work = (hw & 7) * (nwg >> 3) + (hw >> 3);
  int row0 = (int)(work % ny) * 128;   // col-clustered: consecutive work shares col panel
  int col0 = (int)(work / ny) * 128;
  int lane = tid & 63, wid = tid >> 6;
  int wm = (wid >> 1) * 64, wn = (wid & 1) * 64;
  int fr = lane & 15, lq = lane >> 4;

  int rT = tid >> 3;
  int colS = ((tid & 7) << 4) ^ ((rT & 7) << 4);
  const int8_t* gA = A + (size_t)(row0 + rT) * K + colS;
  const int8_t* gB = B + (size_t)(col0 + rT) * K + colS;
  int8_t* lAd = &lA[tid * 16];
  int8_t* lBd = &lB[tid * 16];

  int swzk = (fr & 7) << 4;
  int aoff[4], boff[4];
#pragma unroll
  for (int m = 0; m < 4; m++) {
    aoff[m] = (wm + m * 16 + fr) * 128;
    boff[m] = (wn + m * 16 + fr) * 128;
  }

  v4i acc[4][4];
#pragma unroll
  for (int m = 0; m < 4; m++)
#pragma unroll
    for (int n = 0; n < 4; n++) acc[m][n] = (v4i){0, 0, 0, 0};

  for (int k0 = 0; k0 < K; k0 += 128) {
#pragma unroll
    for (int i = 0; i < 4; i++) GL16(gA + k0 + (size_t)(32 * i) * K, lAd + i * 4096);
#pragma unroll
    for (int i = 0; i < 4; i++) GL16(gB + k0 + (size_t)(32 * i) * K, lBd + i * 4096);
    __syncthreads();
#pragma unroll
    for (int kk = 0; kk < 2; kk++) {
      int kc = (kk * 64 + lq * 16) ^ swzk;
      v4i a[4], b[4];
#pragma unroll
      for (int m = 0; m < 4; m++) a[m] = *(const v4i*)&lA[aoff[m] + kc];
#pragma unroll
      for (int n = 0; n < 4; n++) b[n] = *(const v4i*)&lB[boff[n] + kc];
#pragma unroll
      for (int m = 0; m < 4; m++)
#pragma unroll
        for (int n = 0; n < 4; n++)
          acc[m][n] = __builtin_amdgcn_mfma_i32_16x16x64_i8(a[m], b[n], acc[m][n], 0, 0, 0);
    }
    __syncthreads();
  }
  int rj = lq * 4;
  int cn = fr;
#pragma unroll
  for (int m = 0; m < 4; m++) {
#pragma unroll
    for (int j = 0; j < 4; j++) {
      int rl = row0 + wm + m * 16 + rj + j;
      float sa = sA[rl];
      size_t rowoff = (size_t)rl * INTER;
#pragma unroll
      for (int np = 0; np < 2; np++) {
        float gv = (float)acc[m][np * 2][j] * sa * sB[col0 + wn + (np * 2) * 16 + cn];
        float uv = (float)acc[m][np * 2 + 1][j] * sa * sB[col0 + wn + (np * 2 + 1) * 16 + cn];
        float inner = 0.7978845608028654f * (gv + 0.044715f * gv * gv * gv);
        float gl = 0.5f * gv * (1.0f + tanhf(inner));
        int jg = (col0 >> 1) + (wn >> 1) + np * 16 + cn;
        act[rowoff + jg] = f2bf_rne(gl * uv);
      }
    }
  }
}

// ---------------- flash attention: paired q-tiles, 256 thr (1 head), 512 blocks ----------
// Ring-3 LDS (76KB -> 2 blocks/CU co-resident), one barrier/tile, fixed-shift softmax.
// XCD-clustered: all 32 blocks of one KV group land on one XCD (K/V L2-resident).
__global__ __launch_bounds__(256, 2) void attn_mfma_kernel(
    const unsigned short* __restrict__ Qhi, const unsigned short* __restrict__ Qlo,
    const unsigned short* __restrict__ Khi, const unsigned short* __restrict__ Klo,
    const unsigned short* __restrict__ Vt, float* __restrict__ out) {
  __shared__ __align__(16) int8_t lkh[3][8192], lkl[3][8192], lvt[3][8192];
  __shared__ unsigned short ps[4][16][32];
  int hwid = blockIdx.y * gridDim.x + blockIdx.x;  // grid = (32,16), 512 wgs
  int work = (hwid & 7) * 64 + (hwid >> 3);        // XCD-bijective remap (2 bg per XCD)
  int bg = work >> 5;
  int rest = work & 31;
  int pi = rest >> 1;
  int hh = rest & 1;
  int qtS = pi, qtL = 31 - pi;                     // paired q-tiles: 66 tiles, constant
  int b = bg >> 3, g = bg & 7;
  int tid = threadIdx.x;
  int lane = tid & 63, w = tid >> 6;               // 4 waves
  int lr = lane & 15, lq = lane >> 4;
  int h = g * 2 + hh;
  int qbS = qtS * 64 + w * 16;
  int qbL = qtL * 64 + w * 16;

  const int8_t* kbh = (const int8_t*)(Khi + (size_t)bg * SEQ * HD);
  const int8_t* kbl = (const int8_t*)(Klo + (size_t)bg * SEQ * HD);
  const int8_t* vb = (const int8_t*)(Vt + (size_t)bg * HD * SEQ);

  int x0 = tid * 16, x1 = x0 + 4096;
  int sK0 = x0 ^ (((x0 >> 8) & 7) << 4);
  int sK1 = x1 ^ (((x1 >> 8) & 7) << 4);

  // Q fragments for both tiles (hi/lo) in registers
  s8v qhS[4], qlS[4], qhL[4], qlL[4];
  {
    size_t qoS = (size_t)(b * SEQ + qbS + lr) * QDIM + h * HD + lq * 8;
    size_t qoL = (size_t)(b * SEQ + qbL + lr) * QDIM + h * HD + lq * 8;
#pragma unroll
    for (int c = 0; c < 4; ++c) {
      qhS[c] = *(const s8v*)(Qhi + qoS + c * 32);
      qlS[c] = *(const s8v*)(Qlo + qoS + c * 32);
      qhL[c] = *(const s8v*)(Qhi + qoL + c * 32);
      qlL[c] = *(const s8v*)(Qlo + qoL + c * 32);
    }
  }

  v4f oaccS[8], oaccL[8];
#pragma unroll
  for (int i = 0; i < 8; ++i) {
    oaccS[i] = (v4f){0.f, 0.f, 0.f, 0.f};
    oaccL[i] = (v4f){0.f, 0.f, 0.f, 0.f};
  }
  float lsumS[4] = {0.f, 0.f, 0.f, 0.f};
  float lsumL[4] = {0.f, 0.f, 0.f, 0.f};
  const float kin2 = 0.0035355339059327374f;  // 2/(sqrt(128)*50)

  int kswz = (lr & 7) << 4;
  int kcol = lq * 16;
  int vbase = lq * 2048 + lr * 16;  // + dt*256

  int ktiles = 2 * qtL + 2;

#define STAGE(kt, buf)                                  \
  do {                                                  \
    size_t kb = (size_t)(kt) * 8192;                    \
    GL16(kbh + kb + sK0, &lkh[buf][x0]);                \
    GL16(kbh + kb + sK1, &lkh[buf][x1]);                \
    GL16(kbl + kb + sK0, &lkl[buf][x0]);                \
    GL16(kbl + kb + sK1, &lkl[buf][x1]);                \
    GL16(vb + kb + x0, &lvt[buf][x0]);                  \
    GL16(vb + kb + x1, &lvt[buf][x1]);                  \
  } while (0)

#define TILE_COMPUTE(qb, qh, ql, oacc, lsum)                                           \
  do {                                                                                 \
    v4f sacc[2];                                                                       \
    __builtin_amdgcn_s_setprio(1);                                                     \
    _Pragma("unroll") for (int t2 = 0; t2 < 2; ++t2) {                                 \
      v4f s1 = (v4f){0.f, 0.f, 0.f, 0.f};                                              \
      v4f s2 = (v4f){0.f, 0.f, 0.f, 0.f};                                              \
      v4f s3 = (v4f){0.f, 0.f, 0.f, 0.f};                                              \
      int rowb = (t2 * 16 + lr) * 256;                                                 \
      _Pragma("unroll") for (int c = 0; c < 4; ++c) {                                  \
        int off = rowb + ((c * 64 + kcol) ^ kswz);                                     \
        s8v kh = *(const s8v*)&lkh[cur][off];                                          \
        s8v kl = *(const s8v*)&lkl[cur][off];                                          \
        s1 = __builtin_amdgcn_mfma_f32_16x16x32_bf16(qh[c], kh, s1, 0, 0, 0);          \
        s2 = __builtin_amdgcn_mfma_f32_16x16x32_bf16(qh[c], kl, s2, 0, 0, 0);          \
        s3 = __builtin_amdgcn_mfma_f32_16x16x32_bf16(ql[c], kh, s3, 0, 0, 0);          \
      }                                                                                \
      sacc[t2] = (s1 + s2) + s3;                                                       \
    }                                                                                  \
    __builtin_amdgcn_s_setprio(0);                                                     \
    _Pragma("unroll") for (int j = 0; j < 4; ++j) {                                    \
      int qg = (qb) + lq * 4 + j;                                                      \
      int k0g = kbase + lr, k1g = kbase + 16 + lr;                                     \
      float z0 = __expf(sacc[0][j] * kin2);                                            \
      float z1 = __expf(sacc[1][j] * kin2);                                            \
      float e0 = __expf(-100.f * __builtin_amdgcn_rcpf(z0 + 1.f));                     \
      float e1 = __expf(-100.f * __builtin_amdgcn_rcpf(z1 + 1.f));                     \
      e0 = (k0g <= qg) ? e0 : 0.f;                                                     \
      e1 = (k1g <= qg) ? e1 : 0.f;                                                     \
      lsum[j] += e0 + e1;                                                              \
      int q = lq * 4 + j;                                                              \
      ps[w][q][lr] = f2bf_rne(e0);                                                     \
      ps[w][q][16 + lr] = f2bf_rne(e1);                                                \
    }                                                                                  \
    s8v pa = *(const s8v*)&ps[w][lr][lq * 8];                                          \
    __builtin_amdgcn_s_setprio(1);                                                     \
    _Pragma("unroll") for (int dt = 0; dt < 8; ++dt) {                                 \
      s8v vh = *(const s8v*)&lvt[cur][vbase + dt * 256];                               \
      oacc[dt] = __builtin_amdgcn_mfma_f32_16x16x32_bf16(pa, vh, oacc[dt], 0, 0, 0);   \
    }                                                                                  \
    __builtin_amdgcn_s_setprio(0);                                                     \
  } while (0)

  STAGE(0, 0);
  STAGE(1, 1);
  int cur = 0;
  for (int kt = 0; kt < ktiles; ++kt) {
    if (kt + 1 < ktiles) {
      asm volatile("s_waitcnt vmcnt(6)" ::: "memory");
    } else {
      asm volatile("s_waitcnt vmcnt(0)" ::: "memory");
    }
    __builtin_amdgcn_s_barrier();
    __builtin_amdgcn_sched_barrier(0);
    int stg = cur + 2;
    if (stg >= 3) stg -= 3;
    if (kt + 2 < ktiles) STAGE(kt + 2, stg);
    int kbase = kt * 32;
    TILE_COMPUTE(qbL, qhL, qlL, oaccL, lsumL);
    if (kbase <= qbS + 15) TILE_COMPUTE(qbS, qhS, qlS, oaccS, lsumS);
    cur = (cur == 2) ? 0 : cur + 1;
  }
#undef TILE_COMPUTE
#undef STAGE

#pragma unroll
  for (int st = 1; st <= 8; st <<= 1)
#pragma unroll
    for (int j = 0; j < 4; ++j) {
      lsumS[j] += __shfl_xor(lsumS[j], st);
      lsumL[j] += __shfl_xor(lsumL[j], st);
    }

  float invS[4], invL[4];
#pragma unroll
  for (int j = 0; j < 4; ++j) {
    invS[j] = 1.f / lsumS[j];
    invL[j] = 1.f / lsumL[j];
  }
  float* obS = out + (size_t)(b * SEQ + qbS) * QDIM + h * HD;
  float* obL = out + (size_t)(b * SEQ + qbL) * QDIM + h * HD;
#pragma unroll
  for (int dt = 0; dt < 8; ++dt)
#pragma unroll
    for (int j = 0; j < 4; ++j) {
      obS[(size_t)(lq * 4 + j) * QDIM + dt * 16 + lr] = oaccS[dt][j] * invS[j];
      obL[(size_t)(lq * 4 + j) * QDIM + dt * 16 + lr] = oaccL[dt][j] * invL[j];
    }
}

extern "C" void kernel_launch(void* const* d_in, const int* in_sizes, int n_in, void* d_out,
                              int out_size, void* d_ws, size_t ws_size, hipStream_t stream) {
  (void)in_sizes; (void)n_in; (void)out_size; (void)ws_size;
  const float* hidden = (const float*)d_in[0];
  const float* w_in_norm = (const float*)d_in[1];
  const float* w_post_norm = (const float*)d_in[2];
  const float* wqkv = (const float*)d_in[3];
  const float* wo = (const float*)d_in[4];
  const float* w_gate_up = (const float*)d_in[5];
  const float* w_down = (const float*)d_in[6];
  float* out = (float*)d_out;

  char* p = (char*)d_ws;
  size_t off = 0;
  auto take = [&](size_t bytes) -> char* {
    char* r = p + off;
    off += (bytes + 255) & ~(size_t)255;
    return r;
  };
  const size_t MB = 1u << 20;
  int8_t* qx = (int8_t*)take((size_t)T_TOKENS * DM);
  float* sx = (float*)take((size_t)T_TOKENS * 4);
  int8_t* qw_qkv = (int8_t*)take((size_t)QKVN * DM);
  float* sw_qkv = (float*)take((size_t)QKVN * 4);
  int8_t* qw_wo = (int8_t*)take((size_t)DM * QDIM);
  float* sw_wo = (float*)take((size_t)DM * 4);
  int8_t* qw_gu = (int8_t*)take((size_t)GUN * DM);
  float* sw_gu = (float*)take((size_t)GUN * 4);
  int8_t* qw_dn = (int8_t*)take((size_t)DM * INTER);
  float* sw_dn = (float*)take((size_t)DM * 4);
  float* cosT = (float*)take((size_t)SEQ * 64 * 4);
  float* sinT = (float*)take((size_t)SEQ * 64 * 4);
  float* x1 = (float*)take((size_t)T_TOKENS * DM * 4);
  float* s_act = (float*)take((size_t)T_TOKENS * 4);
  char* regB = take(96 * MB);
  float* qf32 = (float*)regB;
  float* kvf32 = (float*)regB;
  float* attn_out = (float*)regB;
  unsigned short* Qhi = (unsigned short*)(regB + 32 * MB);
  unsigned short* Qlo = (unsigned short*)(regB + 48 * MB);
  unsigned short* Khi = (unsigned short*)(regB + 64 * MB);
  unsigned short* Klo = (unsigned short*)(regB + 72 * MB);
  unsigned short* Vt = (unsigned short*)(regB + 80 * MB);
  unsigned short* act_bf16 = (unsigned short*)regB;    // phase-2: [0,64MB) full 4096 rows
  int8_t* act_q8 = (int8_t*)(regB + 64 * MB);          // phase-2: [64,96MB)

  rope_table_kernel<<<SEQ, 64, 0, stream>>>(cosT, sinT);
  quant_w_kernel<<<QKVN, 256, 0, stream>>>(wqkv, qw_qkv, sw_qkv, DM);
  quant_w_kernel<<<DM, 256, 0, stream>>>(wo, qw_wo, sw_wo, QDIM);
  quant_w_gu_kernel<<<GUN, 256, 0, stream>>>(w_gate_up, qw_gu, sw_gu);
  quant_w_kernel<<<DM, 256, 0, stream>>>(w_down, qw_dn, sw_dn, INTER);

  // attention block
  rmsnorm_quant_kernel<<<T_TOKENS, 256, 0, stream>>>(hidden, w_in_norm, qx, sx);
  gemm_i8_kernel<256><<<dim3(QDIM / 128, T_TOKENS / 128), 256, 0, stream>>>(
      qx, sx, qw_qkv, sw_qkv, nullptr, qf32, QDIM, DM);
  cvt_q_kernel<<<T_TOKENS, 256, 0, stream>>>(qf32, cosT, sinT, Qhi, Qlo);
  gemm_i8_kernel<256><<<dim3(DM / 128, T_TOKENS / 128), 256, 0, stream>>>(
      qx, sx, qw_qkv + (size_t)QDIM * DM, sw_qkv + QDIM, nullptr, kvf32, DM, DM);
  cvt_k_kernel<<<T_TOKENS, 256, 0, stream>>>(kvf32, cosT, sinT, Khi, Klo);
  cvt_v_kernel<<<dim3(SEQ / 32, 16), 256, 0, stream>>>(kvf32, Vt);
  attn_mfma_kernel<<<dim3(32, 16), 256, 0, stream>>>(Qhi, Qlo, Khi, Klo, Vt, attn_out);
  quant_rows_2048_kernel<<<T_TOKENS, 256, 0, stream>>>(attn_out, qx, sx);
  gemm_i8_kernel<256><<<dim3(DM / 128, T_TOKENS / 128), 256, 0, stream>>>(
      qx, sx, qw_wo, sw_wo, hidden, x1, DM, QDIM);

  // MLP block: single GU launch -> bf16 act (64MB) -> quant -> single down GEMM
  rmsnorm_quant_kernel<<<T_TOKENS, 256, 0, stream>>>(x1, w_post_norm, qx, sx);
  gemm_gu_fused_kernel<<<dim3(GUN / 128, T_TOKENS / 128), 256, 0, stream>>>(qx, sx, qw_gu, sw_gu,
                                                                            act_bf16);
  quant_rows_8192_bf16_kernel<<<T_TOKENS, 256, 0, stream>>>(act_bf16, act_q8, s_act);
  gemm_i8_kernel<256><<<dim3(DM / 128, T_TOKENS / 128), 256, 0, stream>>>(
      act_q8, s_act, qw_dn, sw_dn, x1, out, DM, INTER);
}

// Round 16
// 582.764 us; speedup vs baseline: 1.1808x; 1.0732x over previous
//
#include <hip/hip_runtime.h>
#include <cstdint>
#include <math.h>

#define T_TOKENS 4096
#define SEQ 2048
#define DM 2048
#define NH 16
#define NKV 8
#define HD 128
#define QDIM 2048   // NH*HD
#define KVDIM 1024  // NKV*HD
#define QKVN 4096   // QDIM + 2*KVDIM
#define INTER 8192
#define GUN 16384   // 2*INTER

typedef int v4i __attribute__((ext_vector_type(4)));
typedef float v4f __attribute__((ext_vector_type(4)));
typedef short s8v __attribute__((ext_vector_type(8)));
typedef short s4v __attribute__((ext_vector_type(4)));
typedef short s2v __attribute__((ext_vector_type(2)));

#define GL16(g, l)                                                                       \
  __builtin_amdgcn_global_load_lds((__attribute__((address_space(1))) const void*)(g),   \
                                   (__attribute__((address_space(3))) void*)(l), 16, 0, 0)

__device__ inline float wave_sum(float v) {
#pragma unroll
  for (int off = 32; off > 0; off >>= 1) v += __shfl_down(v, off);
  return v;
}
__device__ inline float wave_max(float v) {
#pragma unroll
  for (int off = 32; off > 0; off >>= 1) v = fmaxf(v, __shfl_down(v, off));
  return v;
}
__device__ inline float dot4(float4 a, float4 b) {
  return a.x * b.x + a.y * b.y + a.z * b.z + a.w * b.w;
}
__device__ inline int8_t quant1(float v, float s) {
  float q = rintf(v / s);
  q = fminf(fmaxf(q, -127.f), 127.f);
  return (int8_t)(int)q;
}
__device__ inline unsigned short f2bf_rne(float x) {
  unsigned u = __float_as_uint(x);
  return (unsigned short)((u + 0x7FFFu + ((u >> 16) & 1u)) >> 16);
}
__device__ inline float bf2f(unsigned short h) { return __uint_as_float(((unsigned)h) << 16); }

// ---------------- RoPE tables ----------------
__global__ void rope_table_kernel(float* __restrict__ cosT, float* __restrict__ sinT) {
  int s = blockIdx.x, d = threadIdx.x;  // 64 threads
  float inv = 1.0f / powf(10000.0f, (float)d * (1.0f / 64.0f));
  float f = (float)s * inv;
  cosT[s * 64 + d] = cosf(f);
  sinT[s * 64 + d] = sinf(f);
}

// ---------------- per-row weight quant (single-read, register cached) ----------------
__global__ __launch_bounds__(256) void quant_w_kernel(const float* __restrict__ w,
                                                      int8_t* __restrict__ qw,
                                                      float* __restrict__ sw, int K) {
  __shared__ float red[4];
  int row = blockIdx.x, tid = threadIdx.x;
  const float* wr = w + (size_t)row * K;
  int nv = K >> 10;
  float4 v[8];
  float mx = 0.f;
#pragma unroll
  for (int i = 0; i < 8; i++) {
    if (i < nv) {
      v[i] = *(const float4*)(wr + (size_t)(tid + i * 256) * 4);
      mx = fmaxf(mx, fmaxf(fmaxf(fabsf(v[i].x), fabsf(v[i].y)),
                           fmaxf(fabsf(v[i].z), fabsf(v[i].w))));
    }
  }
  mx = wave_max(mx);
  if ((tid & 63) == 0) red[tid >> 6] = mx;
  __syncthreads();
  float m = fmaxf(fmaxf(red[0], red[1]), fmaxf(red[2], red[3]));
  float s = m * (1.0f / 127.0f);
  if (tid == 0) sw[row] = s;
  float sd = (s > 0.f) ? s : 1.f;
  int8_t* qr = qw + (size_t)row * K;
#pragma unroll
  for (int i = 0; i < 8; i++) {
    if (i < nv) {
      char4 o;
      o.x = quant1(v[i].x, sd);
      o.y = quant1(v[i].y, sd);
      o.z = quant1(v[i].z, sd);
      o.w = quant1(v[i].w, sd);
      *(char4*)(qr + (size_t)(tid + i * 256) * 4) = o;
    }
  }
}

// ---------------- gate_up weight quant with 16-col interleaved permutation ----------------
__global__ __launch_bounds__(256) void quant_w_gu_kernel(const float* __restrict__ w,
                                                         int8_t* __restrict__ qw,
                                                         float* __restrict__ sw) {
  __shared__ float red[4];
  int row = blockIdx.x, tid = threadIdx.x;
  const int K = DM;
  int j = (row < INTER) ? row : row - INTER;
  int pr = (j >> 6) * 128 + ((j >> 4) & 3) * 32 + ((row < INTER) ? 0 : 16) + (j & 15);
  const float* wr = w + (size_t)row * K;
  float4 v[2];
  float mx = 0.f;
#pragma unroll
  for (int i = 0; i < 2; i++) {
    v[i] = *(const float4*)(wr + (size_t)(tid + i * 256) * 4);
    mx = fmaxf(mx, fmaxf(fmaxf(fabsf(v[i].x), fabsf(v[i].y)),
                         fmaxf(fabsf(v[i].z), fabsf(v[i].w))));
  }
  mx = wave_max(mx);
  if ((tid & 63) == 0) red[tid >> 6] = mx;
  __syncthreads();
  float m = fmaxf(fmaxf(red[0], red[1]), fmaxf(red[2], red[3]));
  float s = m * (1.0f / 127.0f);
  if (tid == 0) sw[pr] = s;
  float sd = (s > 0.f) ? s : 1.f;
  int8_t* qr = qw + (size_t)pr * K;
#pragma unroll
  for (int i = 0; i < 2; i++) {
    char4 o;
    o.x = quant1(v[i].x, sd);
    o.y = quant1(v[i].y, sd);
    o.z = quant1(v[i].z, sd);
    o.w = quant1(v[i].w, sd);
    *(char4*)(qr + (size_t)(tid + i * 256) * 4) = o;
  }
}

// ---------------- RMSNorm + per-token quant ----------------
__global__ __launch_bounds__(256) void rmsnorm_quant_kernel(const float* __restrict__ x,
                                                            const float* __restrict__ w,
                                                            int8_t* __restrict__ q,
                                                            float* __restrict__ s) {
  __shared__ float red[8];
  int t = blockIdx.x, tid = threadIdx.x;
  const float* xr = x + (size_t)t * DM;
  float4 a = *(const float4*)(xr + tid * 8);
  float4 b = *(const float4*)(xr + tid * 8 + 4);
  float ss = dot4(a, a) + dot4(b, b);
  ss = wave_sum(ss);
  if ((tid & 63) == 0) red[tid >> 6] = ss;
  __syncthreads();
  float tot = red[0] + red[1] + red[2] + red[3];
  float rms = rsqrtf(tot * (1.0f / DM) + 1e-6f);
  float4 wa = *(const float4*)(w + tid * 8);
  float4 wb = *(const float4*)(w + tid * 8 + 4);
  float y[8] = {a.x * rms * wa.x, a.y * rms * wa.y, a.z * rms * wa.z, a.w * rms * wa.w,
                b.x * rms * wb.x, b.y * rms * wb.y, b.z * rms * wb.z, b.w * rms * wb.w};
  float mx = 0.f;
#pragma unroll
  for (int i = 0; i < 8; i++) mx = fmaxf(mx, fabsf(y[i]));
  mx = wave_max(mx);
  if ((tid & 63) == 0) red[4 + (tid >> 6)] = mx;
  __syncthreads();
  float m = fmaxf(fmaxf(red[4], red[5]), fmaxf(red[6], red[7]));
  float sc = fmaxf(m * (1.0f / 127.0f), 1e-8f);
  if (tid == 0) s[t] = sc;
  int8_t* qr = q + (size_t)t * DM + tid * 8;
  char4 o0, o1;
  o0.x = quant1(y[0], sc); o0.y = quant1(y[1], sc); o0.z = quant1(y[2], sc); o0.w = quant1(y[3], sc);
  o1.x = quant1(y[4], sc); o1.y = quant1(y[5], sc); o1.z = quant1(y[6], sc); o1.w = quant1(y[7], sc);
  *(char4*)(qr) = o0;
  *(char4*)(qr + 4) = o1;
}

// ---------------- plain per-token quant of a [*,2048] f32 matrix ----------------
__global__ __launch_bounds__(256) void quant_rows_2048_kernel(const float* __restrict__ x,
                                                              int8_t* __restrict__ q,
                                                              float* __restrict__ s) {
  __shared__ float red[4];
  int t = blockIdx.x, tid = threadIdx.x;
  const float* xr = x + (size_t)t * DM;
  float4 a = *(const float4*)(xr + tid * 8);
  float4 b = *(const float4*)(xr + tid * 8 + 4);
  float y[8] = {a.x, a.y, a.z, a.w, b.x, b.y, b.z, b.w};
  float mx = 0.f;
#pragma unroll
  for (int i = 0; i < 8; i++) mx = fmaxf(mx, fabsf(y[i]));
  mx = wave_max(mx);
  if ((tid & 63) == 0) red[tid >> 6] = mx;
  __syncthreads();
  float m = fmaxf(fmaxf(red[0], red[1]), fmaxf(red[2], red[3]));
  float sc = fmaxf(m * (1.0f / 127.0f), 1e-8f);
  if (tid == 0) s[t] = sc;
  int8_t* qr = q + (size_t)t * DM + tid * 8;
  char4 o0, o1;
  o0.x = quant1(y[0], sc); o0.y = quant1(y[1], sc); o0.z = quant1(y[2], sc); o0.w = quant1(y[3], sc);
  o1.x = quant1(y[4], sc); o1.y = quant1(y[5], sc); o1.z = quant1(y[6], sc); o1.w = quant1(y[7], sc);
  *(char4*)(qr) = o0;
  *(char4*)(qr + 4) = o1;
}

// ---------------- per-token quant of a [*,8192] bf16 matrix ----------------
__global__ __launch_bounds__(256) void quant_rows_8192_bf16_kernel(
    const unsigned short* __restrict__ x, int8_t* __restrict__ q, float* __restrict__ s) {
  __shared__ float red[4];
  int t = blockIdx.x, tid = threadIdx.x;
  const unsigned short* xr = x + (size_t)t * INTER + tid * 32;
  float y[32];
  float mx = 0.f;
#pragma unroll
  for (int i8 = 0; i8 < 32; i8 += 8) {
    s8v v = *(const s8v*)(xr + i8);
#pragma unroll
    for (int j = 0; j < 8; j++) {
      float f = bf2f((unsigned short)v[j]);
      y[i8 + j] = f;
      mx = fmaxf(mx, fabsf(f));
    }
  }
  mx = wave_max(mx);
  if ((tid & 63) == 0) red[tid >> 6] = mx;
  __syncthreads();
  float m = fmaxf(fmaxf(red[0], red[1]), fmaxf(red[2], red[3]));
  float sc = fmaxf(m * (1.0f / 127.0f), 1e-8f);
  if (tid == 0) s[t] = sc;
  int8_t* qr = q + (size_t)t * INTER + tid * 32;
#pragma unroll
  for (int i4 = 0; i4 < 32; i4 += 4) {
    char4 o;
    o.x = quant1(y[i4], sc);
    o.y = quant1(y[i4 + 1], sc);
    o.z = quant1(y[i4 + 2], sc);
    o.w = quant1(y[i4 + 3], sc);
    *(char4*)(qr + i4) = o;
  }
}

// ---------------- RoPE + f32->bf16 hi/lo conversion: Q ----------------
__global__ __launch_bounds__(256) void cvt_q_kernel(const float* __restrict__ qf,
                                                    const float* __restrict__ cosT,
                                                    const float* __restrict__ sinT,
                                                    unsigned short* __restrict__ Qhi,
                                                    unsigned short* __restrict__ Qlo) {
  int t = blockIdx.x, tid = threadIdx.x;
  int sp = t & (SEQ - 1);
  int h = tid >> 4, pb = (tid & 15) * 4;
  const float* row = qf + (size_t)t * QDIM + h * HD;
  float4 x0 = *(const float4*)(row + pb);
  float4 x1 = *(const float4*)(row + pb + 64);
  float4 c = *(const float4*)(cosT + sp * 64 + pb);
  float4 s = *(const float4*)(sinT + sp * 64 + pb);
  float y0[4] = {x0.x * c.x - x1.x * s.x, x0.y * c.y - x1.y * s.y, x0.z * c.z - x1.z * s.z,
                 x0.w * c.w - x1.w * s.w};
  float y1[4] = {x1.x * c.x + x0.x * s.x, x1.y * c.y + x0.y * s.y, x1.z * c.z + x0.z * s.z,
                 x1.w * c.w + x0.w * s.w};
  s4v h0, l0, h1, l1;
#pragma unroll
  for (int e = 0; e < 4; e++) {
    unsigned short hb = f2bf_rne(y0[e]);
    h0[e] = (short)hb;
    l0[e] = (short)f2bf_rne(y0[e] - bf2f(hb));
    hb = f2bf_rne(y1[e]);
    h1[e] = (short)hb;
    l1[e] = (short)f2bf_rne(y1[e] - bf2f(hb));
  }
  size_t o = (size_t)t * QDIM + h * HD + pb;
  *(s4v*)&Qhi[o] = h0;
  *(s4v*)&Qlo[o] = l0;
  *(s4v*)&Qhi[o + 64] = h1;
  *(s4v*)&Qlo[o + 64] = l1;
}

// ---------------- RoPE + conversion: K (layout [(b,g)][s][d]) ----------------
__global__ __launch_bounds__(256) void cvt_k_kernel(const float* __restrict__ kvf,
                                                    const float* __restrict__ cosT,
                                                    const float* __restrict__ sinT,
                                                    unsigned short* __restrict__ Khi,
                                                    unsigned short* __restrict__ Klo) {
  int t = blockIdx.x, tid = threadIdx.x;
  int sp = t & (SEQ - 1);
  int b = t >> 11;
  int g = tid >> 5, pb = (tid & 31) * 2;
  const float* row = kvf + (size_t)t * DM + g * HD;
  float2 x0 = *(const float2*)(row + pb);
  float2 x1 = *(const float2*)(row + pb + 64);
  float2 c = *(const float2*)(cosT + sp * 64 + pb);
  float2 s = *(const float2*)(sinT + sp * 64 + pb);
  float y0[2] = {x0.x * c.x - x1.x * s.x, x0.y * c.y - x1.y * s.y};
  float y1[2] = {x1.x * c.x + x0.x * s.x, x1.y * c.y + x0.y * s.y};
  s2v h0, l0, h1, l1;
#pragma unroll
  for (int e = 0; e < 2; e++) {
    unsigned short hb = f2bf_rne(y0[e]);
    h0[e] = (short)hb;
    l0[e] = (short)f2bf_rne(y0[e] - bf2f(hb));
    hb = f2bf_rne(y1[e]);
    h1[e] = (short)hb;
    l1[e] = (short)f2bf_rne(y1[e] - bf2f(hb));
  }
  size_t o = ((size_t)(b * NKV + g) * SEQ + sp) * HD + pb;
  *(s2v*)&Khi[o] = h0;
  *(s2v*)&Klo[o] = l0;
  *(s2v*)&Khi[o + 64] = h1;
  *(s2v*)&Klo[o + 64] = l1;
}

// ---------------- V transpose + conversion ----------------
// Vt layout per bg: per 32-k tile (8192B): [kc 0-3][d 0-127][e 0-7] bf16
__global__ __launch_bounds__(256) void cvt_v_kernel(const float* __restrict__ kvf,
                                                    unsigned short* __restrict__ Vt) {
  __shared__ float vt[32][132];
  int bg = blockIdx.y;
  int b = bg >> 3, g = bg & 7;
  int s0 = blockIdx.x * 32;
  int tid = threadIdx.x;
#pragma unroll
  for (int i = 0; i < 4; i++) {
    int pos = tid + i * 256;
    int r = pos >> 5, d4 = (pos & 31) * 4;
    *(float4*)&vt[r][d4] =
        *(const float4*)(kvf + (size_t)(b * SEQ + s0 + r) * DM + KVDIM + g * HD + d4);
  }
  __syncthreads();
  int d = tid & 127, half = tid >> 7;
  unsigned short u[16];
#pragma unroll
  for (int i = 0; i < 16; i++) u[i] = f2bf_rne(vt[half * 16 + i][d]);
  unsigned short* dst =
      Vt + (size_t)bg * HD * SEQ + (size_t)(s0 >> 5) * 4096 + (half * 2) * 1024 + d * 8;
  *(s8v*)dst = *(s8v*)&u[0];
  *(s8v*)(dst + 1024) = *(s8v*)&u[8];
}

// ---------------- int8 GEMM (global_load_lds + XOR swizzle, 128x128, templated BK) --------
template <int BK>
__global__ __launch_bounds__(256) void gemm_i8_kernel(const int8_t* __restrict__ A,
                                                      const float* __restrict__ sA,
                                                      const int8_t* __restrict__ B,
                                                      const float* __restrict__ sB,
                                                      const float* __restrict__ res,
                                                      float* __restrict__ C, int N, int K) {
  constexpr int NCH = BK / 16;   // 16B chunks per tile row
  constexpr int RS = 4096 / BK;  // rows covered per issue round (256 thr x 16B)
  constexpr int ISS = BK / 32;   // issue rounds per matrix
  __shared__ __align__(16) int8_t lA[128 * BK];
  __shared__ __align__(16) int8_t lB[128 * BK];
  int tid = threadIdx.x;
  unsigned nx = gridDim.x;
  unsigned hw = blockIdx.y * nx + blockIdx.x;
  unsigned nwg = nx * gridDim.y;
  unsigned work = (hw & 7) * (nwg >> 3) + (hw >> 3);
  int row0 = (int)(work / nx) * 128;
  int col0 = (int)(work % nx) * 128;
  int lane = tid & 63, wid = tid >> 6;
  int wm = (wid >> 1) * 64, wn = (wid & 1) * 64;
  int fr = lane & 15, lq = lane >> 4;

  int rT = tid / NCH;
  int cT = tid % NCH;
  int colS = ((cT ^ (rT & (NCH - 1))) << 4);
  const int8_t* gA = A + (size_t)(row0 + rT) * K + colS;
  const int8_t* gB = B + (size_t)(col0 + rT) * K + colS;
  int8_t* lAd = &lA[tid * 16];
  int8_t* lBd = &lB[tid * 16];

  int swzk = (fr & (NCH - 1)) << 4;
  int aoff[4], boff[4];
#pragma unroll
  for (int m = 0; m < 4; m++) {
    aoff[m] = (wm + m * 16 + fr) * BK;
    boff[m] = (wn + m * 16 + fr) * BK;
  }

  v4i acc[4][4];
#pragma unroll
  for (int m = 0; m < 4; m++)
#pragma unroll
    for (int n = 0; n < 4; n++) acc[m][n] = (v4i){0, 0, 0, 0};

  for (int k0 = 0; k0 < K; k0 += BK) {
#pragma unroll
    for (int i = 0; i < ISS; i++) GL16(gA + k0 + (size_t)(RS * i) * K, lAd + i * 4096);
#pragma unroll
    for (int i = 0; i < ISS; i++) GL16(gB + k0 + (size_t)(RS * i) * K, lBd + i * 4096);
    __syncthreads();
#pragma unroll
    for (int kk = 0; kk < BK / 64; kk++) {
      int kc = (kk * 64 + lq * 16) ^ swzk;
      v4i a[4], b[4];
#pragma unroll
      for (int m = 0; m < 4; m++) a[m] = *(const v4i*)&lA[aoff[m] + kc];
#pragma unroll
      for (int n = 0; n < 4; n++) b[n] = *(const v4i*)&lB[boff[n] + kc];
#pragma unroll
      for (int m = 0; m < 4; m++)
#pragma unroll
        for (int n = 0; n < 4; n++)
          acc[m][n] = __builtin_amdgcn_mfma_i32_16x16x64_i8(a[m], b[n], acc[m][n], 0, 0, 0);
    }
    __syncthreads();
  }
  int rj = lq * 4;
  int cn = fr;
#pragma unroll
  for (int m = 0; m < 4; m++) {
#pragma unroll
    for (int j = 0; j < 4; j++) {
      int rl = row0 + wm + m * 16 + rj + j;
      float sa = sA[rl];
      size_t rowoff = (size_t)rl * N;
#pragma unroll
      for (int n = 0; n < 4; n++) {
        int cg = col0 + wn + n * 16 + cn;
        float v = (float)acc[m][n][j] * sa * sB[cg];
        if (res) v += res[rowoff + cg];
        C[rowoff + cg] = v;
      }
    }
  }
}

// ---------------- int8 GEMM + fused gelu(gate)*up epilogue -> bf16 act ----------
// SUPERTILED XCD decode: each XCD owns 16 col-panels; works ordered in 16-col x 8-row
// supertiles (col-outer, row-inner) so concurrent L2 set = 8 B-panels + 8 A-blocks = 4MB.
__global__ __launch_bounds__(256) void gemm_gu_fused_kernel(const int8_t* __restrict__ A,
                                                            const float* __restrict__ sA,
                                                            const int8_t* __restrict__ B,
                                                            const float* __restrict__ sB,
                                                            unsigned short* __restrict__ act) {
  __shared__ __align__(16) int8_t lA[16384];
  __shared__ __align__(16) int8_t lB[16384];
  const int K = DM;
  int tid = threadIdx.x;
  unsigned nx = gridDim.x;                         // 128 col panels
  unsigned hw = blockIdx.y * nx + blockIdx.x;      // 4096 wgs
  unsigned xcd = hw & 7;
  unsigned local = hw >> 3;                        // 0..511
  unsigned st = local >> 7;                        // band 0..3 (8 rows each)
  unsigned lc = local & 127;
  unsigned colL = lc >> 3;                         // 0..15 (col-outer)
  unsigned rowL = lc & 7;                          // row-inner
  int col0 = (int)(xcd * 16 + colL) * 128;
  int row0 = (int)(st * 8 + rowL) * 128;
  int lane = tid & 63, wid = tid >> 6;
  int wm = (wid >> 1) * 64, wn = (wid & 1) * 64;
  int fr = lane & 15, lq = lane >> 4;

  int rT = tid >> 3;
  int colS = ((tid & 7) << 4) ^ ((rT & 7) << 4);
  const int8_t* gA = A + (size_t)(row0 + rT) * K + colS;
  const int8_t* gB = B + (size_t)(col0 + rT) * K + colS;
  int8_t* lAd = &lA[tid * 16];
  int8_t* lBd = &lB[tid * 16];

  int swzk = (fr & 7) << 4;
  int aoff[4], boff[4];
#pragma unroll
  for (int m = 0; m < 4; m++) {
    aoff[m] = (wm + m * 16 + fr) * 128;
    boff[m] = (wn + m * 16 + fr) * 128;
  }

  v4i acc[4][4];
#pragma unroll
  for (int m = 0; m < 4; m++)
#pragma unroll
    for (int n = 0; n < 4; n++) acc[m][n] = (v4i){0, 0, 0, 0};

  for (int k0 = 0; k0 < K; k0 += 128) {
#pragma unroll
    for (int i = 0; i < 4; i++) GL16(gA + k0 + (size_t)(32 * i) * K, lAd + i * 4096);
#pragma unroll
    for (int i = 0; i < 4; i++) GL16(gB + k0 + (size_t)(32 * i) * K, lBd + i * 4096);
    __syncthreads();
#pragma unroll
    for (int kk = 0; kk < 2; kk++) {
      int kc = (kk * 64 + lq * 16) ^ swzk;
      v4i a[4], b[4];
#pragma unroll
      for (int m = 0; m < 4; m++) a[m] = *(const v4i*)&lA[aoff[m] + kc];
#pragma unroll
      for (int n = 0; n < 4; n++) b[n] = *(const v4i*)&lB[boff[n] + kc];
#pragma unroll
      for (int m = 0; m < 4; m++)
#pragma unroll
        for (int n = 0; n < 4; n++)
          acc[m][n] = __builtin_amdgcn_mfma_i32_16x16x64_i8(a[m], b[n], acc[m][n], 0, 0, 0);
    }
    __syncthreads();
  }
  int rj = lq * 4;
  int cn = fr;
#pragma unroll
  for (int m = 0; m < 4; m++) {
#pragma unroll
    for (int j = 0; j < 4; j++) {
      int rl = row0 + wm + m * 16 + rj + j;
      float sa = sA[rl];
      size_t rowoff = (size_t)rl * INTER;
#pragma unroll
      for (int np = 0; np < 2; np++) {
        float gv = (float)acc[m][np * 2][j] * sa * sB[col0 + wn + (np * 2) * 16 + cn];
        float uv = (float)acc[m][np * 2 + 1][j] * sa * sB[col0 + wn + (np * 2 + 1) * 16 + cn];
        float inner = 0.7978845608028654f * (gv + 0.044715f * gv * gv * gv);
        float gl = 0.5f * gv * (1.0f + tanhf(inner));
        int jg = (col0 >> 1) + (wn >> 1) + np * 16 + cn;
        act[rowoff + jg] = f2bf_rne(gl * uv);
      }
    }
  }
}

// ---------------- flash attention: paired q-tiles, 256 thr (1 head), 512 blocks ----------
// Ring-3 LDS (76KB -> 2 blocks/CU co-resident), one barrier/tile, fixed-shift softmax.
// XCD-clustered: all 32 blocks of one KV group land on one XCD (K/V L2-resident).
__global__ __launch_bounds__(256, 2) void attn_mfma_kernel(
    const unsigned short* __restrict__ Qhi, const unsigned short* __restrict__ Qlo,
    const unsigned short* __restrict__ Khi, const unsigned short* __restrict__ Klo,
    const unsigned short* __restrict__ Vt, float* __restrict__ out) {
  __shared__ __align__(16) int8_t lkh[3][8192], lkl[3][8192], lvt[3][8192];
  __shared__ unsigned short ps[4][16][32];
  int hwid = blockIdx.y * gridDim.x + blockIdx.x;  // grid = (32,16), 512 wgs
  int work = (hwid & 7) * 64 + (hwid >> 3);        // XCD-bijective remap (2 bg per XCD)
  int bg = work >> 5;
  int rest = work & 31;
  int pi = rest >> 1;
  int hh = rest & 1;
  int qtS = pi, qtL = 31 - pi;                     // paired q-tiles: 66 tiles, constant
  int b = bg >> 3, g = bg & 7;
  int tid = threadIdx.x;
  int lane = tid & 63, w = tid >> 6;               // 4 waves
  int lr = lane & 15, lq = lane >> 4;
  int h = g * 2 + hh;
  int qbS = qtS * 64 + w * 16;
  int qbL = qtL * 64 + w * 16;

  const int8_t* kbh = (const int8_t*)(Khi + (size_t)bg * SEQ * HD);
  const int8_t* kbl = (const int8_t*)(Klo + (size_t)bg * SEQ * HD);
  const int8_t* vb = (const int8_t*)(Vt + (size_t)bg * HD * SEQ);

  int x0 = tid * 16, x1 = x0 + 4096;
  int sK0 = x0 ^ (((x0 >> 8) & 7) << 4);
  int sK1 = x1 ^ (((x1 >> 8) & 7) << 4);

  // Q fragments for both tiles (hi/lo) in registers
  s8v qhS[4], qlS[4], qhL[4], qlL[4];
  {
    size_t qoS = (size_t)(b * SEQ + qbS + lr) * QDIM + h * HD + lq * 8;
    size_t qoL = (size_t)(b * SEQ + qbL + lr) * QDIM + h * HD + lq * 8;
#pragma unroll
    for (int c = 0; c < 4; ++c) {
      qhS[c] = *(const s8v*)(Qhi + qoS + c * 32);
      qlS[c] = *(const s8v*)(Qlo + qoS + c * 32);
      qhL[c] = *(const s8v*)(Qhi + qoL + c * 32);
      qlL[c] = *(const s8v*)(Qlo + qoL + c * 32);
    }
  }

  v4f oaccS[8], oaccL[8];
#pragma unroll
  for (int i = 0; i < 8; ++i) {
    oaccS[i] = (v4f){0.f, 0.f, 0.f, 0.f};
    oaccL[i] = (v4f){0.f, 0.f, 0.f, 0.f};
  }
  float lsumS[4] = {0.f, 0.f, 0.f, 0.f};
  float lsumL[4] = {0.f, 0.f, 0.f, 0.f};
  const float kin2 = 0.0035355339059327374f;  // 2/(sqrt(128)*50)

  int kswz = (lr & 7) << 4;
  int kcol = lq * 16;
  int vbase = lq * 2048 + lr * 16;  // + dt*256

  int ktiles = 2 * qtL + 2;

#define STAGE(kt, buf)                                  \
  do {                                                  \
    size_t kb = (size_t)(kt) * 8192;                    \
    GL16(kbh + kb + sK0, &lkh[buf][x0]);                \
    GL16(kbh + kb + sK1, &lkh[buf][x1]);                \
    GL16(kbl + kb + sK0, &lkl[buf][x0]);                \
    GL16(kbl + kb + sK1, &lkl[buf][x1]);                \
    GL16(vb + kb + x0, &lvt[buf][x0]);                  \
    GL16(vb + kb + x1, &lvt[buf][x1]);                  \
  } while (0)

#define TILE_COMPUTE(qb, qh, ql, oacc, lsum)                                           \
  do {                                                                                 \
    v4f sacc[2];                                                                       \
    __builtin_amdgcn_s_setprio(1);                                                     \
    _Pragma("unroll") for (int t2 = 0; t2 < 2; ++t2) {                                 \
      v4f s1 = (v4f){0.f, 0.f, 0.f, 0.f};                                              \
      v4f s2 = (v4f){0.f, 0.f, 0.f, 0.f};                                              \
      v4f s3 = (v4f){0.f, 0.f, 0.f, 0.f};                                              \
      int rowb = (t2 * 16 + lr) * 256;                                                 \
      _Pragma("unroll") for (int c = 0; c < 4; ++c) {                                  \
        int off = rowb + ((c * 64 + kcol) ^ kswz);                                     \
        s8v kh = *(const s8v*)&lkh[cur][off];                                          \
        s8v kl = *(const s8v*)&lkl[cur][off];                                          \
        s1 = __builtin_amdgcn_mfma_f32_16x16x32_bf16(qh[c], kh, s1, 0, 0, 0);          \
        s2 = __builtin_amdgcn_mfma_f32_16x16x32_bf16(qh[c], kl, s2, 0, 0, 0);          \
        s3 = __builtin_amdgcn_mfma_f32_16x16x32_bf16(ql[c], kh, s3, 0, 0, 0);          \
      }                                                                                \
      sacc[t2] = (s1 + s2) + s3;                                                       \
    }                                                                                  \
    __builtin_amdgcn_s_setprio(0);                                                     \
    _Pragma("unroll") for (int j = 0; j < 4; ++j) {                                    \
      int qg = (qb) + lq * 4 + j;                                                      \
      int k0g = kbase + lr, k1g = kbase + 16 + lr;                                     \
      float z0 = __expf(sacc[0][j] * kin2);                                            \
      float z1 = __expf(sacc[1][j] * kin2);                                            \
      float e0 = __expf(-100.f * __builtin_amdgcn_rcpf(z0 + 1.f));                     \
      float e1 = __expf(-100.f * __builtin_amdgcn_rcpf(z1 + 1.f));                     \
      e0 = (k0g <= qg) ? e0 : 0.f;                                                     \
      e1 = (k1g <= qg) ? e1 : 0.f;                                                     \
      lsum[j] += e0 + e1;                                                              \
      int q = lq * 4 + j;                                                              \
      ps[w][q][lr] = f2bf_rne(e0);                                                     \
      ps[w][q][16 + lr] = f2bf_rne(e1);                                                \
    }                                                                                  \
    s8v pa = *(const s8v*)&ps[w][lr][lq * 8];                                          \
    __builtin_amdgcn_s_setprio(1);                                                     \
    _Pragma("unroll") for (int dt = 0; dt < 8; ++dt) {                                 \
      s8v vh = *(const s8v*)&lvt[cur][vbase + dt * 256];                               \
      oacc[dt] = __builtin_amdgcn_mfma_f32_16x16x32_bf16(pa, vh, oacc[dt], 0, 0, 0);   \
    }                                                                                  \
    __builtin_amdgcn_s_setprio(0);                                                     \
  } while (0)

  STAGE(0, 0);
  STAGE(1, 1);
  int cur = 0;
  for (int kt = 0; kt < ktiles; ++kt) {
    if (kt + 1 < ktiles) {
      asm volatile("s_waitcnt vmcnt(6)" ::: "memory");
    } else {
      asm volatile("s_waitcnt vmcnt(0)" ::: "memory");
    }
    __builtin_amdgcn_s_barrier();
    __builtin_amdgcn_sched_barrier(0);
    int stg = cur + 2;
    if (stg >= 3) stg -= 3;
    if (kt + 2 < ktiles) STAGE(kt + 2, stg);
    int kbase = kt * 32;
    TILE_COMPUTE(qbL, qhL, qlL, oaccL, lsumL);
    if (kbase <= qbS + 15) TILE_COMPUTE(qbS, qhS, qlS, oaccS, lsumS);
    cur = (cur == 2) ? 0 : cur + 1;
  }
#undef TILE_COMPUTE
#undef STAGE

#pragma unroll
  for (int st = 1; st <= 8; st <<= 1)
#pragma unroll
    for (int j = 0; j < 4; ++j) {
      lsumS[j] += __shfl_xor(lsumS[j], st);
      lsumL[j] += __shfl_xor(lsumL[j], st);
    }

  float invS[4], invL[4];
#pragma unroll
  for (int j = 0; j < 4; ++j) {
    invS[j] = 1.f / lsumS[j];
    invL[j] = 1.f / lsumL[j];
  }
  float* obS = out + (size_t)(b * SEQ + qbS) * QDIM + h * HD;
  float* obL = out + (size_t)(b * SEQ + qbL) * QDIM + h * HD;
#pragma unroll
  for (int dt = 0; dt < 8; ++dt)
#pragma unroll
    for (int j = 0; j < 4; ++j) {
      obS[(size_t)(lq * 4 + j) * QDIM + dt * 16 + lr] = oaccS[dt][j] * invS[j];
      obL[(size_t)(lq * 4 + j) * QDIM + dt * 16 + lr] = oaccL[dt][j] * invL[j];
    }
}

extern "C" void kernel_launch(void* const* d_in, const int* in_sizes, int n_in, void* d_out,
                              int out_size, void* d_ws, size_t ws_size, hipStream_t stream) {
  (void)in_sizes; (void)n_in; (void)out_size; (void)ws_size;
  const float* hidden = (const float*)d_in[0];
  const float* w_in_norm = (const float*)d_in[1];
  const float* w_post_norm = (const float*)d_in[2];
  const float* wqkv = (const float*)d_in[3];
  const float* wo = (const float*)d_in[4];
  const float* w_gate_up = (const float*)d_in[5];
  const float* w_down = (const float*)d_in[6];
  float* out = (float*)d_out;

  char* p = (char*)d_ws;
  size_t off = 0;
  auto take = [&](size_t bytes) -> char* {
    char* r = p + off;
    off += (bytes + 255) & ~(size_t)255;
    return r;
  };
  const size_t MB = 1u << 20;
  int8_t* qx = (int8_t*)take((size_t)T_TOKENS * DM);
  float* sx = (float*)take((size_t)T_TOKENS * 4);
  int8_t* qw_qkv = (int8_t*)take((size_t)QKVN * DM);
  float* sw_qkv = (float*)take((size_t)QKVN * 4);
  int8_t* qw_wo = (int8_t*)take((size_t)DM * QDIM);
  float* sw_wo = (float*)take((size_t)DM * 4);
  int8_t* qw_gu = (int8_t*)take((size_t)GUN * DM);
  float* sw_gu = (float*)take((size_t)GUN * 4);
  int8_t* qw_dn = (int8_t*)take((size_t)DM * INTER);
  float* sw_dn = (float*)take((size_t)DM * 4);
  float* cosT = (float*)take((size_t)SEQ * 64 * 4);
  float* sinT = (float*)take((size_t)SEQ * 64 * 4);
  float* x1 = (float*)take((size_t)T_TOKENS * DM * 4);
  float* s_act = (float*)take((size_t)T_TOKENS * 4);
  char* regB = take(96 * MB);
  float* qf32 = (float*)regB;
  float* kvf32 = (float*)regB;
  float* attn_out = (float*)regB;
  unsigned short* Qhi = (unsigned short*)(regB + 32 * MB);
  unsigned short* Qlo = (unsigned short*)(regB + 48 * MB);
  unsigned short* Khi = (unsigned short*)(regB + 64 * MB);
  unsigned short* Klo = (unsigned short*)(regB + 72 * MB);
  unsigned short* Vt = (unsigned short*)(regB + 80 * MB);
  unsigned short* act_bf16 = (unsigned short*)regB;    // phase-2: [0,64MB) full 4096 rows
  int8_t* act_q8 = (int8_t*)(regB + 64 * MB);          // phase-2: [64,96MB)

  rope_table_kernel<<<SEQ, 64, 0, stream>>>(cosT, sinT);
  quant_w_kernel<<<QKVN, 256, 0, stream>>>(wqkv, qw_qkv, sw_qkv, DM);
  quant_w_kernel<<<DM, 256, 0, stream>>>(wo, qw_wo, sw_wo, QDIM);
  quant_w_gu_kernel<<<GUN, 256, 0, stream>>>(w_gate_up, qw_gu, sw_gu);
  quant_w_kernel<<<DM, 256, 0, stream>>>(w_down, qw_dn, sw_dn, INTER);

  // attention block
  rmsnorm_quant_kernel<<<T_TOKENS, 256, 0, stream>>>(hidden, w_in_norm, qx, sx);
  gemm_i8_kernel<256><<<dim3(QDIM / 128, T_TOKENS / 128), 256, 0, stream>>>(
      qx, sx, qw_qkv, sw_qkv, nullptr, qf32, QDIM, DM);
  cvt_q_kernel<<<T_TOKENS, 256, 0, stream>>>(qf32, cosT, sinT, Qhi, Qlo);
  gemm_i8_kernel<256><<<dim3(DM / 128, T_TOKENS / 128), 256, 0, stream>>>(
      qx, sx, qw_qkv + (size_t)QDIM * DM, sw_qkv + QDIM, nullptr, kvf32, DM, DM);
  cvt_k_kernel<<<T_TOKENS, 256, 0, stream>>>(kvf32, cosT, sinT, Khi, Klo);
  cvt_v_kernel<<<dim3(SEQ / 32, 16), 256, 0, stream>>>(kvf32, Vt);
  attn_mfma_kernel<<<dim3(32, 16), 256, 0, stream>>>(Qhi, Qlo, Khi, Klo, Vt, attn_out);
  quant_rows_2048_kernel<<<T_TOKENS, 256, 0, stream>>>(attn_out, qx, sx);
  gemm_i8_kernel<256><<<dim3(DM / 128, T_TOKENS / 128), 256, 0, stream>>>(
      qx, sx, qw_wo, sw_wo, hidden, x1, DM, QDIM);

  // MLP block: single GU launch (supertiled XCD map) -> bf16 act -> quant -> down GEMM
  rmsnorm_quant_kernel<<<T_TOKENS, 256, 0, stream>>>(x1, w_post_norm, qx, sx);
  gemm_gu_fused_kernel<<<dim3(GUN / 128, T_TOKENS / 128), 256, 0, stream>>>(qx, sx, qw_gu, sw_gu,
                                                                            act_bf16);
  quant_rows_8192_bf16_kernel<<<T_TOKENS, 256, 0, stream>>>(act_bf16, act_q8, s_act);
  gemm_i8_kernel<256><<<dim3(DM / 128, T_TOKENS / 128), 256, 0, stream>>>(
      act_q8, s_act, qw_dn, sw_dn, x1, out, DM, INTER);
}